// Round 14
// baseline (251.750 us; speedup 1.0000x reference)
//
#include <hip/hip_runtime.h>
#include <hip/hip_bf16.h>

typedef unsigned short u16;
typedef unsigned int   u32;
typedef __attribute__((ext_vector_type(2)))  float fx2;
typedef __attribute__((ext_vector_type(4)))  float fx4;
typedef __attribute__((ext_vector_type(16))) float f32x16;
typedef __attribute__((ext_vector_type(4)))  u16   usx4;
typedef __attribute__((ext_vector_type(8)))  u16   usx8;
typedef __attribute__((ext_vector_type(8)))  __bf16 bf16x8;
typedef __attribute__((ext_vector_type(2)))  int   i32x2;
typedef __attribute__((ext_vector_type(2)))  u32   u32x2;
typedef __attribute__((ext_vector_type(4)))  u32   u32x4;

#define DEVI static __device__ __forceinline__

constexpr int Bb = 2, Ss = 2048, Mm = 2048, Ee = 1024, Hh = 16, Dd = 64;
// 1/sqrt(64) * log2(e): projections put Q in the exp2 score domain
#define QSCALE 0.18033688011112042f

DEVI u16 f2bf(float f) {
  u32 u = __builtin_bit_cast(u32, f);
  u32 r = (u + 0x7fffu + ((u >> 16) & 1u)) >> 16;
  return (u16)r;
}
DEVI float bf2f(u16 v) {
  u32 u = ((u32)v) << 16;
  return __builtin_bit_cast(float, u);
}
DEVI bf16x8 as_bf(usx8 v) { return __builtin_bit_cast(bf16x8, v); }

DEVI void gld16(const u16* g, u16* l) {
  __builtin_amdgcn_global_load_lds((const __attribute__((address_space(1))) void*)g,
                                   (__attribute__((address_space(3))) void*)l, 16, 0, 0);
}

#if __has_builtin(__builtin_amdgcn_exp2f)
DEVI float xexp2(float x) { return __builtin_amdgcn_exp2f(x); }
#else
DEVI float xexp2(float x) { return exp2f(x); }
#endif

DEVI u32 cvtpk(float lo, float hi) {
  u32 r;
  asm("v_cvt_pk_bf16_f32 %0, %1, %2" : "=v"(r) : "v"(lo), "v"(hi));
  return r;
}
DEVI bf16x8 pa_from(u32 w0, u32 w1, u32 w2, u32 w3) {
  union { u32 u[4]; usx8 v; } t;
  t.u[0] = w0; t.u[1] = w1; t.u[2] = w2; t.u[3] = w3;
  return as_bf(t.v);
}

// ---------------------------------------------------------------------------
// Pre-cast: f32 -> bf16 for the 3 inputs and 4 weight matrices.
// ---------------------------------------------------------------------------
__global__ __launch_bounds__(256)
void cast_all(const float* __restrict__ q, const float* __restrict__ k,
              const float* __restrict__ v,
              const float* __restrict__ wq, const float* __restrict__ wk,
              const float* __restrict__ wv, const float* __restrict__ wo,
              u16* __restrict__ qc, u16* __restrict__ kc, u16* __restrict__ vc,
              u16* __restrict__ wqc, u16* __restrict__ wkc,
              u16* __restrict__ wvc, u16* __restrict__ woc)
{
  const int y = blockIdx.y;
  const float* s; u16* d; size_t n;
  const size_t NI = (size_t)Bb * Ss * Ee;
  const size_t NW = (size_t)Ee * Ee;
  switch (y) {
    case 0: s = q;  d = qc;  n = NI; break;
    case 1: s = k;  d = kc;  n = NI; break;
    case 2: s = v;  d = vc;  n = NI; break;
    case 3: s = wq; d = wqc; n = NW; break;
    case 4: s = wk; d = wkc; n = NW; break;
    case 5: s = wv; d = wvc; n = NW; break;
    default: s = wo; d = woc; n = NW; break;
  }
  const size_t stride = (size_t)gridDim.x * 256 * 8;
  for (size_t i = ((size_t)blockIdx.x * 256 + threadIdx.x) * 8; i < n; i += stride) {
    fx4 a = *(const fx4*)(s + i);
    fx4 b = *(const fx4*)(s + i + 4);
    u32x4 o;
    o[0] = cvtpk(a[0], a[1]); o[1] = cvtpk(a[2], a[3]);
    o[2] = cvtpk(b[0], b[1]); o[3] = cvtpk(b[2], b[3]);
    *(u32x4*)(d + i) = o;
  }
}

// ---------------------------------------------------------------------------
// Fused Q/K/V projection GEMM (bf16 in): 128x128 tile, BK=64, 4 waves (2x2),
// global_load_lds staging with XOR swizzle, XCD-chunked block swizzle.
// ---------------------------------------------------------------------------
__global__ __launch_bounds__(256, 2)
void gemm_qkv(const u16* __restrict__ qc, const u16* __restrict__ kc,
              const u16* __restrict__ vc,
              const u16* __restrict__ wqc, const u16* __restrict__ wkc,
              const u16* __restrict__ wvc,
              const float* __restrict__ bq, const float* __restrict__ bk,
              const float* __restrict__ bv,
              u16* __restrict__ Qbf, u16* __restrict__ Kbf, u16* __restrict__ Vt)
{
  __shared__ u16 As[2][128][64];
  __shared__ u16 Bs[2][128][64];
  const int tid = threadIdx.x;
  const int w = tid >> 6, l = tid & 63, g = l >> 4, ln = l & 15;
  const int wr = w >> 1, wc = w & 1;

  const int lid = blockIdx.x;
  const int wg = (lid & 7) * 96 + (lid >> 3);
  const int z = wg >> 8;
  const int rem = wg & 255;
  const int row0 = (rem >> 3) * 128;
  const int col0 = (rem & 7) * 128;

  const u16* A = (z == 0) ? qc : (z == 1) ? kc : vc;
  const u16* W = (z == 0) ? wqc : (z == 1) ? wkc : wvc;
  const float* bias = (z == 0) ? bq : (z == 1) ? bk : bv;

  const int colu = (((l & 7) ^ (l >> 3)) << 3);
  auto stage = [&](int buf, int kt) {
#pragma unroll
    for (int j = 0; j < 4; j++) {
      const int c = j * 4 + w;
      const int row = c * 8 + (l >> 3);
      gld16(A + (size_t)(row0 + row) * 1024 + kt * 64 + colu,
            &As[buf][0][0] + c * 512 + l * 8);
      gld16(W + (size_t)(col0 + row) * 1024 + kt * 64 + colu,
            &Bs[buf][0][0] + c * 512 + l * 8);
    }
  };

  fx4 acc[4][4];
#pragma unroll
  for (int i = 0; i < 4; i++)
#pragma unroll
    for (int j = 0; j < 4; j++) acc[i][j] = fx4{0.f, 0.f, 0.f, 0.f};

  stage(0, 0);
  __syncthreads();

  const int swA = (ln & 7) << 3;
  const int NK = 1024 / 64;
  for (int kt = 0; kt < NK; kt++) {
    const int buf = kt & 1;
    if (kt + 1 < NK) stage(buf ^ 1, kt + 1);
#pragma unroll
    for (int ks = 0; ks < 2; ks++) {
      bf16x8 af[4], bfr[4];
      const int cb = (ks * 32 + g * 8) ^ swA;
#pragma unroll
      for (int mi = 0; mi < 4; mi++)
        af[mi] = as_bf(*(const usx8*)&As[buf][wr * 64 + mi * 16 + ln][cb]);
#pragma unroll
      for (int nj = 0; nj < 4; nj++)
        bfr[nj] = as_bf(*(const usx8*)&Bs[buf][wc * 64 + nj * 16 + ln][cb]);
      __builtin_amdgcn_s_setprio(1);
#pragma unroll
      for (int mi = 0; mi < 4; mi++)
#pragma unroll
        for (int nj = 0; nj < 4; nj++)
          acc[mi][nj] = __builtin_amdgcn_mfma_f32_16x16x32_bf16(af[mi], bfr[nj], acc[mi][nj], 0, 0, 0);
      __builtin_amdgcn_s_setprio(0);
    }
    __syncthreads();
  }

#pragma unroll
  for (int mi = 0; mi < 4; mi++) {
#pragma unroll
    for (int nj = 0; nj < 4; nj++) {
      const int j = col0 + wc * 64 + nj * 16 + ln;
      const float bj = bias[j];
      if (z == 2) {
        const int i0 = row0 + wr * 64 + mi * 16 + g * 4;
        const int b2 = i0 >> 11, m2 = i0 & 2047;
        const int h2 = j >> 6,  d2 = j & 63;
        u32x2 pk;
        pk[0] = cvtpk(acc[mi][nj][0] + bj, acc[mi][nj][1] + bj);
        pk[1] = cvtpk(acc[mi][nj][2] + bj, acc[mi][nj][3] + bj);
        *(u32x2*)&Vt[(((size_t)b2 * Hh + h2) * 64 + d2) * (size_t)Mm + m2] = pk;
      } else {
        u16* outp = (z == 0) ? Qbf : Kbf;
        const float sc = (z == 0) ? QSCALE : 1.0f;
#pragma unroll
        for (int r = 0; r < 4; r++) {
          const int i = row0 + wr * 64 + mi * 16 + g * 4 + r;
          outp[(size_t)i * 1024 + j] = f2bf((acc[mi][nj][r] + bj) * sc);
        }
      }
    }
  }
}

// ---------------------------------------------------------------------------
// Output GEMM: y(bf16) = attended(bf16) @ Wo(bf16).T + bo + resid(bf16).
// ---------------------------------------------------------------------------
__global__ __launch_bounds__(256, 2)
void gemm_out(const u16* __restrict__ Ab, const u16* __restrict__ W,
              const float* __restrict__ bias, const u16* __restrict__ resid,
              u16* __restrict__ outb)
{
  __shared__ u16 As[2][128][64];
  __shared__ u16 Bs[2][128][64];
  const int tid = threadIdx.x;
  const int w = tid >> 6, l = tid & 63, g = l >> 4, ln = l & 15;
  const int wr = w >> 1, wc = w & 1;

  const int lid = blockIdx.x;
  const int wg = (lid & 7) * 32 + (lid >> 3);
  const int row0 = (wg >> 3) * 128;
  const int col0 = (wg & 7) * 128;

  const int colu = (((l & 7) ^ (l >> 3)) << 3);
  auto stage = [&](int buf, int kt) {
#pragma unroll
    for (int j = 0; j < 4; j++) {
      const int c = j * 4 + w;
      const int row = c * 8 + (l >> 3);
      gld16(Ab + (size_t)(row0 + row) * 1024 + kt * 64 + colu,
            &As[buf][0][0] + c * 512 + l * 8);
      gld16(W + (size_t)(col0 + row) * 1024 + kt * 64 + colu,
            &Bs[buf][0][0] + c * 512 + l * 8);
    }
  };

  fx4 acc[4][4];
#pragma unroll
  for (int i = 0; i < 4; i++)
#pragma unroll
    for (int j = 0; j < 4; j++) acc[i][j] = fx4{0.f, 0.f, 0.f, 0.f};

  stage(0, 0);
  __syncthreads();

  const int swA = (ln & 7) << 3;
  const int NK = 1024 / 64;
  for (int kt = 0; kt < NK; kt++) {
    const int buf = kt & 1;
    if (kt + 1 < NK) stage(buf ^ 1, kt + 1);
#pragma unroll
    for (int ks = 0; ks < 2; ks++) {
      bf16x8 af[4], bfr[4];
      const int cb = (ks * 32 + g * 8) ^ swA;
#pragma unroll
      for (int mi = 0; mi < 4; mi++)
        af[mi] = as_bf(*(const usx8*)&As[buf][wr * 64 + mi * 16 + ln][cb]);
#pragma unroll
      for (int nj = 0; nj < 4; nj++)
        bfr[nj] = as_bf(*(const usx8*)&Bs[buf][wc * 64 + nj * 16 + ln][cb]);
      __builtin_amdgcn_s_setprio(1);
#pragma unroll
      for (int mi = 0; mi < 4; mi++)
#pragma unroll
        for (int nj = 0; nj < 4; nj++)
          acc[mi][nj] = __builtin_amdgcn_mfma_f32_16x16x32_bf16(af[mi], bfr[nj], acc[mi][nj], 0, 0, 0);
      __builtin_amdgcn_s_setprio(0);
    }
    __syncthreads();
  }

#pragma unroll
  for (int mi = 0; mi < 4; mi++) {
#pragma unroll
    for (int nj = 0; nj < 4; nj++) {
      const int j = col0 + wc * 64 + nj * 16 + ln;
      const float bj = bias[j];
#pragma unroll
      for (int r = 0; r < 4; r++) {
        const int i = row0 + wr * 64 + mi * 16 + g * 4 + r;
        const float v = acc[mi][nj][r] + bj + bf2f(resid[(size_t)i * 1024 + j]);
        outb[(size_t)i * 1024 + j] = f2bf(v);
      }
    }
  }
}

// ---------------------------------------------------------------------------
// Pass 1: flash attention, swapped-QK 32x32, no-max exp2 softmax.
// ---------------------------------------------------------------------------
__global__ __launch_bounds__(256, 2)
void flash_fwd(const u16* __restrict__ Qb, const u16* __restrict__ Kb,
               const u16* __restrict__ Vt, u16* __restrict__ attended,
               float* __restrict__ stats)
{
  __shared__ u16 Ks[2][128][64];   // 32 KB
  __shared__ u16 Vs[2][64][128];   // 32 KB
  const int tid = threadIdx.x;
  const int w = tid >> 6, l = tid & 63;
  const int ln32 = l & 31, hi = l >> 5;
  const int st = blockIdx.x, h = blockIdx.y, b = blockIdx.z;
  const int s0 = st * 128 + w * 32;

  const u16* Kbase = Kb + (size_t)b * Mm * 1024 + h * 64;
  const u16* Vbase = Vt + ((size_t)(b * Hh + h) * 64) * (size_t)Mm;

  const int colu_k = (((l & 7) ^ (l >> 3)) << 3);
  auto stage = [&](int buf, int mt) {
    const int mb = mt * 128;
#pragma unroll
    for (int j = 0; j < 4; j++) {
      const int c = j * 4 + w;
      const int krow = c * 8 + (l >> 3);
      gld16(Kbase + (size_t)(mb + krow) * 1024 + colu_k,
            &Ks[buf][0][0] + c * 512 + l * 8);
      const int vrow = c * 4 + (l >> 4);
      const int colv = (((l & 15) ^ (vrow & 15)) << 3);
      gld16(Vbase + (size_t)vrow * (size_t)Mm + mb + colv,
            &Vs[buf][0][0] + c * 512 + l * 8);
    }
  };

  bf16x8 qa[4];
#pragma unroll
  for (int dstep = 0; dstep < 4; dstep++)
    qa[dstep] = as_bf(*(const usx8*)(Qb + (size_t)(b * Ss + s0 + ln32) * Ee
                                     + h * 64 + dstep * 16 + hi * 8));

  f32x16 acc[2];
#pragma unroll
  for (int i = 0; i < 16; i++) { acc[0][i] = 0.f; acc[1][i] = 0.f; }
  float lsum = 0.f;

  stage(0, 0);
  __syncthreads();

  const int NT = Mm / 128;
  for (int mt = 0; mt < NT; mt++) {
    const int buf = mt & 1;
    if (mt + 1 < NT) stage(buf ^ 1, mt + 1);

    f32x16 sc[4];
#pragma unroll
    for (int mtile = 0; mtile < 4; mtile++) {
      const int row = mtile * 32 + ln32;
      const int sw = (row & 7) << 3;
      f32x16 c;
#pragma unroll
      for (int i = 0; i < 16; i++) c[i] = 0.f;
#pragma unroll
      for (int dstep = 0; dstep < 4; dstep++) {
        bf16x8 kf = as_bf(*(const usx8*)&Ks[buf][row][(dstep * 16 + hi * 8) ^ sw]);
        c = __builtin_amdgcn_mfma_f32_32x32x16_bf16(kf, qa[dstep], c, 0, 0, 0);
      }
      sc[mtile] = c;
    }

#pragma unroll
    for (int mtile = 0; mtile < 4; mtile++) {
      float p[16];
#pragma unroll
      for (int r = 0; r < 16; r++) p[r] = xexp2(sc[mtile][r]);
      float t0 = (p[0] + p[1]) + (p[2] + p[3]);
      float t1 = (p[4] + p[5]) + (p[6] + p[7]);
      float t2 = (p[8] + p[9]) + (p[10] + p[11]);
      float t3 = (p[12] + p[13]) + (p[14] + p[15]);
      lsum += (t0 + t1) + (t2 + t3);

      u32 cp[8];
#pragma unroll
      for (int i = 0; i < 8; i++) cp[i] = cvtpk(p[2 * i], p[2 * i + 1]);
      i32x2 sA = __builtin_amdgcn_permlane32_swap((int)cp[0], (int)cp[2], false, false);
      i32x2 sB = __builtin_amdgcn_permlane32_swap((int)cp[1], (int)cp[3], false, false);
      bf16x8 pa0 = pa_from((u32)sA.x, (u32)sB.x, (u32)sA.y, (u32)sB.y);
      i32x2 sC = __builtin_amdgcn_permlane32_swap((int)cp[4], (int)cp[6], false, false);
      i32x2 sD = __builtin_amdgcn_permlane32_swap((int)cp[5], (int)cp[7], false, false);
      bf16x8 pa1 = pa_from((u32)sC.x, (u32)sD.x, (u32)sC.y, (u32)sD.y);

#pragma unroll
      for (int dtile = 0; dtile < 2; dtile++) {
        const int vrow = dtile * 32 + ln32;
        const int vsw = (vrow & 15) << 3;
        bf16x8 vb0 = as_bf(*(const usx8*)&Vs[buf][vrow][(mtile * 32 + hi * 8) ^ vsw]);
        bf16x8 vb1 = as_bf(*(const usx8*)&Vs[buf][vrow][(mtile * 32 + 16 + hi * 8) ^ vsw]);
        acc[dtile] = __builtin_amdgcn_mfma_f32_32x32x16_bf16(pa0, vb0, acc[dtile], 0, 0, 0);
        acc[dtile] = __builtin_amdgcn_mfma_f32_32x32x16_bf16(pa1, vb1, acc[dtile], 0, 0, 0);
      }
    }
    __syncthreads();
  }

  lsum += __shfl_xor(lsum, 32);
  const float inv = 1.0f / lsum;
  if (l < 32)
    stats[(size_t)(b * Hh + h) * Ss + s0 + l] = inv;
#pragma unroll
  for (int r = 0; r < 16; r++) {
    const int srow = (r & 3) + 8 * (r >> 2) + 4 * hi;
    const float invr = __shfl(inv, srow);
    const int s_abs = s0 + srow;
#pragma unroll
    for (int dtile = 0; dtile < 2; dtile++)
      attended[(size_t)(b * Ss + s_abs) * Ee + h * 64 + dtile * 32 + ln32] =
          f2bf(acc[dtile][r] * invr);
  }
}

// ---------------------------------------------------------------------------
// Pass 2: avg_attention. m-tile 32 (grid 64x16x2 = 2048 = 8 blocks/CU),
// r11 structure kept: 3-slot K ring (12 KB), stage h+2, counted vmcnt,
// raw s_barrier. One 32-m subtile per head: 4 MFMA + 16 exp2/fma per lane.
// ---------------------------------------------------------------------------
__global__ __launch_bounds__(256)
void avg_attn(const u16* __restrict__ Qb, const u16* __restrict__ Kb,
              const float* __restrict__ stats, float* __restrict__ avg_out)
{
  __shared__ u16 Ks[3][32][64];    // 12 KB, 3-slot ring (depth-2 prefetch)
  const int tid = threadIdx.x;
  const int w = tid >> 6, l = tid & 63;
  const int ln32 = l & 31, hi = l >> 5;
  const int mtile0 = blockIdx.x, stile = blockIdx.y, b = blockIdx.z;
  const int m0 = mtile0 * 32;
  const int s0 = stile * 128 + w * 32;
  const int s_lane = s0 + ln32;

  const u16* Kbase = Kb + (size_t)(b * Mm + m0) * 1024;
  const u16* Qrow  = Qb + (size_t)(b * Ss + s_lane) * Ee;
  const float* strow = stats + (size_t)b * Hh * Ss + s_lane;

  // staging: one gld16 per thread (32 rows x 128 B = 4 KB per slot)
  const int srow = tid >> 3;                        // 0..31
  const int colu = (((tid & 7) ^ (srow & 7)) << 3); // XOR-preswizzled source col
  auto stage = [&](int slot, int h) {
    gld16(Kbase + (size_t)srow * 1024 + h * 64 + colu,
          &Ks[slot][0][0] + tid * 8);
  };

  f32x16 acc;
#pragma unroll
  for (int i = 0; i < 16; i++) acc[i] = 0.f;

  // prologue: slots 0,1 staged; require slot 0 landed, leave slot 1 in flight
  stage(0, 0);
  stage(1, 1);
  asm volatile("s_waitcnt vmcnt(1)" ::: "memory");
  __builtin_amdgcn_s_barrier();

  const int row = ln32;
  const int sw = (row & 7) << 3;
  for (int h = 0; h < Hh; h++) {
    const int slot = h % 3;

    // Q + inv for this head FIRST (so the stage below is the newest vmem op)
    bf16x8 qa[4];
#pragma unroll
    for (int d = 0; d < 4; d++)
      qa[d] = as_bf(*(const usx8*)(Qrow + h * 64 + d * 16 + hi * 8));
    const float invh = strow[(size_t)h * Ss];

    if (h + 2 < Hh) stage((h + 2) % 3, h + 2);

    f32x16 c;
#pragma unroll
    for (int i = 0; i < 16; i++) c[i] = 0.f;
    __builtin_amdgcn_s_setprio(1);
#pragma unroll
    for (int dstep = 0; dstep < 4; dstep++) {
      bf16x8 kf = as_bf(*(const usx8*)&Ks[slot][row][(dstep * 16 + hi * 8) ^ sw]);
      c = __builtin_amdgcn_mfma_f32_32x32x16_bf16(kf, qa[dstep], c, 0, 0, 0);
    }
    __builtin_amdgcn_s_setprio(0);
#pragma unroll
    for (int r = 0; r < 16; r++)
      acc[r] += xexp2(c[r]) * invh;

    // counted wait: stage(h+1) landed (in-order); stage(h+2) may stay in flight
    if (h + 2 < Hh) {
      asm volatile("s_waitcnt vmcnt(1)" ::: "memory");
    } else {
      asm volatile("s_waitcnt vmcnt(0)" ::: "memory");
    }
    __builtin_amdgcn_s_barrier();
  }

  float* orow = avg_out + ((size_t)(b * Ss + s_lane)) * Mm + m0;
#pragma unroll
  for (int rq = 0; rq < 4; rq++) {
    fx4 o;
#pragma unroll
    for (int j = 0; j < 4; j++) o[j] = acc[rq * 4 + j] * (1.0f / 16.0f);
    *(fx4*)(orow + rq * 8 + 4 * hi) = o;
  }
}

// ---------------------------------------------------------------------------
// LayerNorm over E=1024, bf16 input y. One block (256 thr) per row.
// ---------------------------------------------------------------------------
__global__ __launch_bounds__(256)
void ln_kernel(const u16* __restrict__ yb, const float* __restrict__ gamma,
               const float* __restrict__ beta, float* __restrict__ out)
{
  const int row = blockIdx.x, tid = threadIdx.x;
  const int w = tid >> 6, l = tid & 63;
  usx4 v4 = *(const usx4*)(yb + (size_t)row * 1024 + tid * 4);
  float v[4];
#pragma unroll
  for (int j = 0; j < 4; j++) v[j] = bf2f(v4[j]);
  float s = v[0] + v[1] + v[2] + v[3];
  float s2 = v[0] * v[0] + v[1] * v[1] + v[2] * v[2] + v[3] * v[3];
#pragma unroll
  for (int off = 32; off >= 1; off >>= 1) {
    s += __shfl_xor(s, off);
    s2 += __shfl_xor(s2, off);
  }
  __shared__ float rs[4], rq[4];
  if (l == 0) { rs[w] = s; rq[w] = s2; }
  __syncthreads();
  s = (rs[0] + rs[1]) + (rs[2] + rs[3]);
  s2 = (rq[0] + rq[1]) + (rq[2] + rq[3]);
  const float mu = s * (1.0f / 1024.0f);
  const float var = s2 * (1.0f / 1024.0f) - mu * mu;
  const float rstd = rsqrtf(var + 1e-5f);
  fx4 gm = *(const fx4*)(gamma + tid * 4);
  fx4 bt = *(const fx4*)(beta + tid * 4);
  fx4 o;
#pragma unroll
  for (int j = 0; j < 4; j++) o[j] = (v[j] - mu) * rstd * gm[j] + bt[j];
  *(fx4*)(out + (size_t)row * 1024 + tid * 4) = o;
}

// ---------------------------------------------------------------------------
extern "C" void kernel_launch(void* const* d_in, const int* in_sizes, int n_in,
                              void* d_out, int out_size, void* d_ws, size_t ws_size,
                              hipStream_t stream)
{
  const float* query = (const float*)d_in[0];
  const float* keys  = (const float*)d_in[1];
  const float* values = (const float*)d_in[2];
  const float* Wq = (const float*)d_in[3];  const float* bq = (const float*)d_in[4];
  const float* Wk = (const float*)d_in[5];  const float* bk = (const float*)d_in[6];
  const float* Wv = (const float*)d_in[7];  const float* bv = (const float*)d_in[8];
  const float* Wo = (const float*)d_in[9];  const float* bo = (const float*)d_in[10];
  const float* gamma = (const float*)d_in[11];
  const float* beta  = (const float*)d_in[12];

  float* out = (float*)d_out;                           // [B,S,E] f32
  float* avg_out = out + (size_t)Bb * Ss * Ee;          // [B,S,M] f32

  const size_t MB = 1024 * 1024;
  char* ws = (char*)d_ws;
  u16*   Qbf    = (u16*)(ws);                 // 0-8 MB   [B*S,E] bf16 (exp2-prescaled)
  u16*   Kbf    = (u16*)(ws + 8  * MB);       // 8-16 MB  [B*M,E] bf16
  u16*   Vt     = (u16*)(ws + 16 * MB);       // 16-24 MB [B,H,D,M] bf16
  u16*   qc     = (u16*)(ws + 24 * MB);       // 24-32 MB cast query (ALIVE until gemm_out: residual)
  u16*   kc     = (u16*)(ws + 32 * MB);       // 32-40 MB cast keys (dead after qkv)
  u16*   vc     = (u16*)(ws + 40 * MB);       // 40-48 MB cast values (dead after qkv)
  u16*   wqc    = (u16*)(ws + 48 * MB);       // 48-50 MB
  u16*   wkc    = (u16*)(ws + 50 * MB);       // 50-52 MB
  u16*   wvc    = (u16*)(ws + 52 * MB);       // 52-54 MB
  u16*   woc    = (u16*)(ws + 54 * MB);       // 54-56 MB (alive until gemm_out)
  float* stats  = (float*)(ws + 56 * MB);     // 56-56.25 MB [B,H,S] 1/l
  u16*   att_bf = (u16*)(ws + 32 * MB);       // 32-40 MB, reuses kc after qkv
  u16*   ybuf   = (u16*)(ws + 40 * MB);       // 40-48 MB bf16 y, reuses vc after qkv

  cast_all<<<dim3(512, 7), 256, 0, stream>>>(query, keys, values, Wq, Wk, Wv, Wo,
                                             qc, kc, vc, wqc, wkc, wvc, woc);

  gemm_qkv<<<dim3(768), 256, 0, stream>>>(qc, kc, vc, wqc, wkc, wvc,
                                          bq, bk, bv, Qbf, Kbf, Vt);

  flash_fwd<<<dim3(Ss / 128, Hh, Bb), 256, 0, stream>>>(Qbf, Kbf, Vt, att_bf, stats);
  avg_attn<<<dim3(Mm / 32, Ss / 128, Bb), 256, 0, stream>>>(Qbf, Kbf, stats, avg_out);

  gemm_out<<<dim3(256), 256, 0, stream>>>(att_bf, woc, bo, qc, ybuf);
  ln_kernel<<<dim3(Bb * Ss), 256, 0, stream>>>(ybuf, gamma, beta, out);
}

// Round 15
// 203.674 us; speedup vs baseline: 1.2360x; 1.2360x over previous
//
#include <hip/hip_runtime.h>
#include <hip/hip_bf16.h>

typedef unsigned short u16;
typedef unsigned int   u32;
typedef __attribute__((ext_vector_type(2)))  float fx2;
typedef __attribute__((ext_vector_type(4)))  float fx4;
typedef __attribute__((ext_vector_type(16))) float f32x16;
typedef __attribute__((ext_vector_type(4)))  u16   usx4;
typedef __attribute__((ext_vector_type(8)))  u16   usx8;
typedef __attribute__((ext_vector_type(8)))  __bf16 bf16x8;
typedef __attribute__((ext_vector_type(2)))  int   i32x2;
typedef __attribute__((ext_vector_type(2)))  u32   u32x2;
typedef __attribute__((ext_vector_type(4)))  u32   u32x4;

#define DEVI static __device__ __forceinline__

constexpr int Bb = 2, Ss = 2048, Mm = 2048, Ee = 1024, Hh = 16, Dd = 64;
// 1/sqrt(64) * log2(e): projections put Q in the exp2 score domain
#define QSCALE 0.18033688011112042f

DEVI u16 f2bf(float f) {
  u32 u = __builtin_bit_cast(u32, f);
  u32 r = (u + 0x7fffu + ((u >> 16) & 1u)) >> 16;
  return (u16)r;
}
DEVI float bf2f(u16 v) {
  u32 u = ((u32)v) << 16;
  return __builtin_bit_cast(float, u);
}
DEVI bf16x8 as_bf(usx8 v) { return __builtin_bit_cast(bf16x8, v); }

DEVI void gld16(const u16* g, u16* l) {
  __builtin_amdgcn_global_load_lds((const __attribute__((address_space(1))) void*)g,
                                   (__attribute__((address_space(3))) void*)l, 16, 0, 0);
}

#if __has_builtin(__builtin_amdgcn_exp2f)
DEVI float xexp2(float x) { return __builtin_amdgcn_exp2f(x); }
#else
DEVI float xexp2(float x) { return exp2f(x); }
#endif

DEVI u32 cvtpk(float lo, float hi) {
  u32 r;
  asm("v_cvt_pk_bf16_f32 %0, %1, %2" : "=v"(r) : "v"(lo), "v"(hi));
  return r;
}
DEVI bf16x8 pa_from(u32 w0, u32 w1, u32 w2, u32 w3) {
  union { u32 u[4]; usx8 v; } t;
  t.u[0] = w0; t.u[1] = w1; t.u[2] = w2; t.u[3] = w3;
  return as_bf(t.v);
}

// ---------------------------------------------------------------------------
// Pre-cast: f32 -> bf16 for the 3 inputs and 4 weight matrices.
// ---------------------------------------------------------------------------
__global__ __launch_bounds__(256)
void cast_all(const float* __restrict__ q, const float* __restrict__ k,
              const float* __restrict__ v,
              const float* __restrict__ wq, const float* __restrict__ wk,
              const float* __restrict__ wv, const float* __restrict__ wo,
              u16* __restrict__ qc, u16* __restrict__ kc, u16* __restrict__ vc,
              u16* __restrict__ wqc, u16* __restrict__ wkc,
              u16* __restrict__ wvc, u16* __restrict__ woc)
{
  const int y = blockIdx.y;
  const float* s; u16* d; size_t n;
  const size_t NI = (size_t)Bb * Ss * Ee;
  const size_t NW = (size_t)Ee * Ee;
  switch (y) {
    case 0: s = q;  d = qc;  n = NI; break;
    case 1: s = k;  d = kc;  n = NI; break;
    case 2: s = v;  d = vc;  n = NI; break;
    case 3: s = wq; d = wqc; n = NW; break;
    case 4: s = wk; d = wkc; n = NW; break;
    case 5: s = wv; d = wvc; n = NW; break;
    default: s = wo; d = woc; n = NW; break;
  }
  const size_t stride = (size_t)gridDim.x * 256 * 8;
  for (size_t i = ((size_t)blockIdx.x * 256 + threadIdx.x) * 8; i < n; i += stride) {
    fx4 a = *(const fx4*)(s + i);
    fx4 b = *(const fx4*)(s + i + 4);
    u32x4 o;
    o[0] = cvtpk(a[0], a[1]); o[1] = cvtpk(a[2], a[3]);
    o[2] = cvtpk(b[0], b[1]); o[3] = cvtpk(b[2], b[3]);
    *(u32x4*)(d + i) = o;
  }
}

// ---------------------------------------------------------------------------
// Fused Q/K/V projection GEMM (bf16 in): 128x128 tile, BK=64, 4 waves (2x2),
// global_load_lds staging with XOR swizzle, XCD-chunked block swizzle.
// ---------------------------------------------------------------------------
__global__ __launch_bounds__(256, 2)
void gemm_qkv(const u16* __restrict__ qc, const u16* __restrict__ kc,
              const u16* __restrict__ vc,
              const u16* __restrict__ wqc, const u16* __restrict__ wkc,
              const u16* __restrict__ wvc,
              const float* __restrict__ bq, const float* __restrict__ bk,
              const float* __restrict__ bv,
              u16* __restrict__ Qbf, u16* __restrict__ Kbf, u16* __restrict__ Vt)
{
  __shared__ u16 As[2][128][64];
  __shared__ u16 Bs[2][128][64];
  const int tid = threadIdx.x;
  const int w = tid >> 6, l = tid & 63, g = l >> 4, ln = l & 15;
  const int wr = w >> 1, wc = w & 1;

  const int lid = blockIdx.x;
  const int wg = (lid & 7) * 96 + (lid >> 3);
  const int z = wg >> 8;
  const int rem = wg & 255;
  const int row0 = (rem >> 3) * 128;
  const int col0 = (rem & 7) * 128;

  const u16* A = (z == 0) ? qc : (z == 1) ? kc : vc;
  const u16* W = (z == 0) ? wqc : (z == 1) ? wkc : wvc;
  const float* bias = (z == 0) ? bq : (z == 1) ? bk : bv;

  const int colu = (((l & 7) ^ (l >> 3)) << 3);
  auto stage = [&](int buf, int kt) {
#pragma unroll
    for (int j = 0; j < 4; j++) {
      const int c = j * 4 + w;
      const int row = c * 8 + (l >> 3);
      gld16(A + (size_t)(row0 + row) * 1024 + kt * 64 + colu,
            &As[buf][0][0] + c * 512 + l * 8);
      gld16(W + (size_t)(col0 + row) * 1024 + kt * 64 + colu,
            &Bs[buf][0][0] + c * 512 + l * 8);
    }
  };

  fx4 acc[4][4];
#pragma unroll
  for (int i = 0; i < 4; i++)
#pragma unroll
    for (int j = 0; j < 4; j++) acc[i][j] = fx4{0.f, 0.f, 0.f, 0.f};

  stage(0, 0);
  __syncthreads();

  const int swA = (ln & 7) << 3;
  const int NK = 1024 / 64;
  for (int kt = 0; kt < NK; kt++) {
    const int buf = kt & 1;
    if (kt + 1 < NK) stage(buf ^ 1, kt + 1);
#pragma unroll
    for (int ks = 0; ks < 2; ks++) {
      bf16x8 af[4], bfr[4];
      const int cb = (ks * 32 + g * 8) ^ swA;
#pragma unroll
      for (int mi = 0; mi < 4; mi++)
        af[mi] = as_bf(*(const usx8*)&As[buf][wr * 64 + mi * 16 + ln][cb]);
#pragma unroll
      for (int nj = 0; nj < 4; nj++)
        bfr[nj] = as_bf(*(const usx8*)&Bs[buf][wc * 64 + nj * 16 + ln][cb]);
      __builtin_amdgcn_s_setprio(1);
#pragma unroll
      for (int mi = 0; mi < 4; mi++)
#pragma unroll
        for (int nj = 0; nj < 4; nj++)
          acc[mi][nj] = __builtin_amdgcn_mfma_f32_16x16x32_bf16(af[mi], bfr[nj], acc[mi][nj], 0, 0, 0);
      __builtin_amdgcn_s_setprio(0);
    }
    __syncthreads();
  }

#pragma unroll
  for (int mi = 0; mi < 4; mi++) {
#pragma unroll
    for (int nj = 0; nj < 4; nj++) {
      const int j = col0 + wc * 64 + nj * 16 + ln;
      const float bj = bias[j];
      if (z == 2) {
        const int i0 = row0 + wr * 64 + mi * 16 + g * 4;
        const int b2 = i0 >> 11, m2 = i0 & 2047;
        const int h2 = j >> 6,  d2 = j & 63;
        u32x2 pk;
        pk[0] = cvtpk(acc[mi][nj][0] + bj, acc[mi][nj][1] + bj);
        pk[1] = cvtpk(acc[mi][nj][2] + bj, acc[mi][nj][3] + bj);
        *(u32x2*)&Vt[(((size_t)b2 * Hh + h2) * 64 + d2) * (size_t)Mm + m2] = pk;
      } else {
        u16* outp = (z == 0) ? Qbf : Kbf;
        const float sc = (z == 0) ? QSCALE : 1.0f;
#pragma unroll
        for (int r = 0; r < 4; r++) {
          const int i = row0 + wr * 64 + mi * 16 + g * 4 + r;
          outp[(size_t)i * 1024 + j] = f2bf((acc[mi][nj][r] + bj) * sc);
        }
      }
    }
  }
}

// ---------------------------------------------------------------------------
// Output GEMM: y(bf16) = attended(bf16) @ Wo(bf16).T + bo + resid(bf16).
// ---------------------------------------------------------------------------
__global__ __launch_bounds__(256, 2)
void gemm_out(const u16* __restrict__ Ab, const u16* __restrict__ W,
              const float* __restrict__ bias, const u16* __restrict__ resid,
              u16* __restrict__ outb)
{
  __shared__ u16 As[2][128][64];
  __shared__ u16 Bs[2][128][64];
  const int tid = threadIdx.x;
  const int w = tid >> 6, l = tid & 63, g = l >> 4, ln = l & 15;
  const int wr = w >> 1, wc = w & 1;

  const int lid = blockIdx.x;
  const int wg = (lid & 7) * 32 + (lid >> 3);
  const int row0 = (wg >> 3) * 128;
  const int col0 = (wg & 7) * 128;

  const int colu = (((l & 7) ^ (l >> 3)) << 3);
  auto stage = [&](int buf, int kt) {
#pragma unroll
    for (int j = 0; j < 4; j++) {
      const int c = j * 4 + w;
      const int row = c * 8 + (l >> 3);
      gld16(Ab + (size_t)(row0 + row) * 1024 + kt * 64 + colu,
            &As[buf][0][0] + c * 512 + l * 8);
      gld16(W + (size_t)(col0 + row) * 1024 + kt * 64 + colu,
            &Bs[buf][0][0] + c * 512 + l * 8);
    }
  };

  fx4 acc[4][4];
#pragma unroll
  for (int i = 0; i < 4; i++)
#pragma unroll
    for (int j = 0; j < 4; j++) acc[i][j] = fx4{0.f, 0.f, 0.f, 0.f};

  stage(0, 0);
  __syncthreads();

  const int swA = (ln & 7) << 3;
  const int NK = 1024 / 64;
  for (int kt = 0; kt < NK; kt++) {
    const int buf = kt & 1;
    if (kt + 1 < NK) stage(buf ^ 1, kt + 1);
#pragma unroll
    for (int ks = 0; ks < 2; ks++) {
      bf16x8 af[4], bfr[4];
      const int cb = (ks * 32 + g * 8) ^ swA;
#pragma unroll
      for (int mi = 0; mi < 4; mi++)
        af[mi] = as_bf(*(const usx8*)&As[buf][wr * 64 + mi * 16 + ln][cb]);
#pragma unroll
      for (int nj = 0; nj < 4; nj++)
        bfr[nj] = as_bf(*(const usx8*)&Bs[buf][wc * 64 + nj * 16 + ln][cb]);
      __builtin_amdgcn_s_setprio(1);
#pragma unroll
      for (int mi = 0; mi < 4; mi++)
#pragma unroll
        for (int nj = 0; nj < 4; nj++)
          acc[mi][nj] = __builtin_amdgcn_mfma_f32_16x16x32_bf16(af[mi], bfr[nj], acc[mi][nj], 0, 0, 0);
      __builtin_amdgcn_s_setprio(0);
    }
    __syncthreads();
  }

#pragma unroll
  for (int mi = 0; mi < 4; mi++) {
#pragma unroll
    for (int nj = 0; nj < 4; nj++) {
      const int j = col0 + wc * 64 + nj * 16 + ln;
      const float bj = bias[j];
#pragma unroll
      for (int r = 0; r < 4; r++) {
        const int i = row0 + wr * 64 + mi * 16 + g * 4 + r;
        const float v = acc[mi][nj][r] + bj + bf2f(resid[(size_t)i * 1024 + j]);
        outb[(size_t)i * 1024 + j] = f2bf(v);
      }
    }
  }
}

// ---------------------------------------------------------------------------
// Pass 1: flash attention, swapped-QK 32x32, no-max exp2 softmax.
// ---------------------------------------------------------------------------
__global__ __launch_bounds__(256, 2)
void flash_fwd(const u16* __restrict__ Qb, const u16* __restrict__ Kb,
               const u16* __restrict__ Vt, u16* __restrict__ attended,
               float* __restrict__ stats)
{
  __shared__ u16 Ks[2][128][64];   // 32 KB
  __shared__ u16 Vs[2][64][128];   // 32 KB
  const int tid = threadIdx.x;
  const int w = tid >> 6, l = tid & 63;
  const int ln32 = l & 31, hi = l >> 5;
  const int st = blockIdx.x, h = blockIdx.y, b = blockIdx.z;
  const int s0 = st * 128 + w * 32;

  const u16* Kbase = Kb + (size_t)b * Mm * 1024 + h * 64;
  const u16* Vbase = Vt + ((size_t)(b * Hh + h) * 64) * (size_t)Mm;

  const int colu_k = (((l & 7) ^ (l >> 3)) << 3);
  auto stage = [&](int buf, int mt) {
    const int mb = mt * 128;
#pragma unroll
    for (int j = 0; j < 4; j++) {
      const int c = j * 4 + w;
      const int krow = c * 8 + (l >> 3);
      gld16(Kbase + (size_t)(mb + krow) * 1024 + colu_k,
            &Ks[buf][0][0] + c * 512 + l * 8);
      const int vrow = c * 4 + (l >> 4);
      const int colv = (((l & 15) ^ (vrow & 15)) << 3);
      gld16(Vbase + (size_t)vrow * (size_t)Mm + mb + colv,
            &Vs[buf][0][0] + c * 512 + l * 8);
    }
  };

  bf16x8 qa[4];
#pragma unroll
  for (int dstep = 0; dstep < 4; dstep++)
    qa[dstep] = as_bf(*(const usx8*)(Qb + (size_t)(b * Ss + s0 + ln32) * Ee
                                     + h * 64 + dstep * 16 + hi * 8));

  f32x16 acc[2];
#pragma unroll
  for (int i = 0; i < 16; i++) { acc[0][i] = 0.f; acc[1][i] = 0.f; }
  float lsum = 0.f;

  stage(0, 0);
  __syncthreads();

  const int NT = Mm / 128;
  for (int mt = 0; mt < NT; mt++) {
    const int buf = mt & 1;
    if (mt + 1 < NT) stage(buf ^ 1, mt + 1);

    f32x16 sc[4];
#pragma unroll
    for (int mtile = 0; mtile < 4; mtile++) {
      const int row = mtile * 32 + ln32;
      const int sw = (row & 7) << 3;
      f32x16 c;
#pragma unroll
      for (int i = 0; i < 16; i++) c[i] = 0.f;
#pragma unroll
      for (int dstep = 0; dstep < 4; dstep++) {
        bf16x8 kf = as_bf(*(const usx8*)&Ks[buf][row][(dstep * 16 + hi * 8) ^ sw]);
        c = __builtin_amdgcn_mfma_f32_32x32x16_bf16(kf, qa[dstep], c, 0, 0, 0);
      }
      sc[mtile] = c;
    }

#pragma unroll
    for (int mtile = 0; mtile < 4; mtile++) {
      float p[16];
#pragma unroll
      for (int r = 0; r < 16; r++) p[r] = xexp2(sc[mtile][r]);
      float t0 = (p[0] + p[1]) + (p[2] + p[3]);
      float t1 = (p[4] + p[5]) + (p[6] + p[7]);
      float t2 = (p[8] + p[9]) + (p[10] + p[11]);
      float t3 = (p[12] + p[13]) + (p[14] + p[15]);
      lsum += (t0 + t1) + (t2 + t3);

      u32 cp[8];
#pragma unroll
      for (int i = 0; i < 8; i++) cp[i] = cvtpk(p[2 * i], p[2 * i + 1]);
      i32x2 sA = __builtin_amdgcn_permlane32_swap((int)cp[0], (int)cp[2], false, false);
      i32x2 sB = __builtin_amdgcn_permlane32_swap((int)cp[1], (int)cp[3], false, false);
      bf16x8 pa0 = pa_from((u32)sA.x, (u32)sB.x, (u32)sA.y, (u32)sB.y);
      i32x2 sC = __builtin_amdgcn_permlane32_swap((int)cp[4], (int)cp[6], false, false);
      i32x2 sD = __builtin_amdgcn_permlane32_swap((int)cp[5], (int)cp[7], false, false);
      bf16x8 pa1 = pa_from((u32)sC.x, (u32)sD.x, (u32)sC.y, (u32)sD.y);

#pragma unroll
      for (int dtile = 0; dtile < 2; dtile++) {
        const int vrow = dtile * 32 + ln32;
        const int vsw = (vrow & 15) << 3;
        bf16x8 vb0 = as_bf(*(const usx8*)&Vs[buf][vrow][(mtile * 32 + hi * 8) ^ vsw]);
        bf16x8 vb1 = as_bf(*(const usx8*)&Vs[buf][vrow][(mtile * 32 + 16 + hi * 8) ^ vsw]);
        acc[dtile] = __builtin_amdgcn_mfma_f32_32x32x16_bf16(pa0, vb0, acc[dtile], 0, 0, 0);
        acc[dtile] = __builtin_amdgcn_mfma_f32_32x32x16_bf16(pa1, vb1, acc[dtile], 0, 0, 0);
      }
    }
    __syncthreads();
  }

  lsum += __shfl_xor(lsum, 32);
  const float inv = 1.0f / lsum;
  if (l < 32)
    stats[(size_t)(b * Hh + h) * Ss + s0 + l] = inv;
#pragma unroll
  for (int r = 0; r < 16; r++) {
    const int srow = (r & 3) + 8 * (r >> 2) + 4 * hi;
    const float invr = __shfl(inv, srow);
    const int s_abs = s0 + srow;
#pragma unroll
    for (int dtile = 0; dtile < 2; dtile++)
      attended[(size_t)(b * Ss + s_abs) * Ee + h * 64 + dtile * 32 + ln32] =
          f2bf(acc[dtile][r] * invr);
  }
}

// ---------------------------------------------------------------------------
// Pass 2: avg_attention. m-tile 32, grid 64x16x2 = 2048 = 8 blocks/CU.
// ROLLED head loop (#pragma unroll 1 -- r14's 164-VGPR regression was the
// compiler fully unrolling h%3; pinning keeps ~56 VGPR). 3-slot K ring
// (12 KB), stage h+2, counted vmcnt, raw s_barrier.
// ---------------------------------------------------------------------------
__global__ __launch_bounds__(256)
void avg_attn(const u16* __restrict__ Qb, const u16* __restrict__ Kb,
              const float* __restrict__ stats, float* __restrict__ avg_out)
{
  __shared__ u16 Ks[3][32][64];    // 12 KB, 3-slot ring (depth-2 prefetch)
  const int tid = threadIdx.x;
  const int w = tid >> 6, l = tid & 63;
  const int ln32 = l & 31, hi = l >> 5;
  const int mtile0 = blockIdx.x, stile = blockIdx.y, b = blockIdx.z;
  const int m0 = mtile0 * 32;
  const int s0 = stile * 128 + w * 32;
  const int s_lane = s0 + ln32;

  const u16* Kbase = Kb + (size_t)(b * Mm + m0) * 1024;
  const u16* Qrow  = Qb + (size_t)(b * Ss + s_lane) * Ee;
  const float* strow = stats + (size_t)b * Hh * Ss + s_lane;

  // staging: one gld16 per thread (32 rows x 128 B = 4 KB per slot)
  const int srow = tid >> 3;                        // 0..31
  const int colu = (((tid & 7) ^ (srow & 7)) << 3); // XOR-preswizzled source col
  auto stage = [&](int slot, int h) {
    gld16(Kbase + (size_t)srow * 1024 + h * 64 + colu,
          &Ks[slot][0][0] + tid * 8);
  };

  f32x16 acc;
#pragma unroll
  for (int i = 0; i < 16; i++) acc[i] = 0.f;

  // prologue: slots 0,1 staged; require slot 0 landed, leave slot 1 in flight
  stage(0, 0);
  stage(1, 1);
  asm volatile("s_waitcnt vmcnt(1)" ::: "memory");
  __builtin_amdgcn_s_barrier();

  const int row = ln32;
  const int sw = (row & 7) << 3;
#pragma unroll 1
  for (int h = 0; h < Hh; h++) {
    const int slot = h % 3;

    // Q + inv for this head FIRST (so the stage below is the newest vmem op)
    bf16x8 qa[4];
#pragma unroll
    for (int d = 0; d < 4; d++)
      qa[d] = as_bf(*(const usx8*)(Qrow + h * 64 + d * 16 + hi * 8));
    const float invh = strow[(size_t)h * Ss];

    if (h + 2 < Hh) stage((h + 2) % 3, h + 2);

    f32x16 c;
#pragma unroll
    for (int i = 0; i < 16; i++) c[i] = 0.f;
    __builtin_amdgcn_s_setprio(1);
#pragma unroll
    for (int dstep = 0; dstep < 4; dstep++) {
      bf16x8 kf = as_bf(*(const usx8*)&Ks[slot][row][(dstep * 16 + hi * 8) ^ sw]);
      c = __builtin_amdgcn_mfma_f32_32x32x16_bf16(kf, qa[dstep], c, 0, 0, 0);
    }
    __builtin_amdgcn_s_setprio(0);
#pragma unroll
    for (int r = 0; r < 16; r++)
      acc[r] += xexp2(c[r]) * invh;

    // counted wait: stage(h+1) landed (in-order); stage(h+2) may stay in flight
    if (h + 2 < Hh) {
      asm volatile("s_waitcnt vmcnt(1)" ::: "memory");
    } else {
      asm volatile("s_waitcnt vmcnt(0)" ::: "memory");
    }
    __builtin_amdgcn_s_barrier();
  }

  float* orow = avg_out + ((size_t)(b * Ss + s_lane)) * Mm + m0;
#pragma unroll
  for (int rq = 0; rq < 4; rq++) {
    fx4 o;
#pragma unroll
    for (int j = 0; j < 4; j++) o[j] = acc[rq * 4 + j] * (1.0f / 16.0f);
    *(fx4*)(orow + rq * 8 + 4 * hi) = o;
  }
}

// ---------------------------------------------------------------------------
// LayerNorm over E=1024, bf16 input y. One block (256 thr) per row.
// ---------------------------------------------------------------------------
__global__ __launch_bounds__(256)
void ln_kernel(const u16* __restrict__ yb, const float* __restrict__ gamma,
               const float* __restrict__ beta, float* __restrict__ out)
{
  const int row = blockIdx.x, tid = threadIdx.x;
  const int w = tid >> 6, l = tid & 63;
  usx4 v4 = *(const usx4*)(yb + (size_t)row * 1024 + tid * 4);
  float v[4];
#pragma unroll
  for (int j = 0; j < 4; j++) v[j] = bf2f(v4[j]);
  float s = v[0] + v[1] + v[2] + v[3];
  float s2 = v[0] * v[0] + v[1] * v[1] + v[2] * v[2] + v[3] * v[3];
#pragma unroll
  for (int off = 32; off >= 1; off >>= 1) {
    s += __shfl_xor(s, off);
    s2 += __shfl_xor(s2, off);
  }
  __shared__ float rs[4], rq[4];
  if (l == 0) { rs[w] = s; rq[w] = s2; }
  __syncthreads();
  s = (rs[0] + rs[1]) + (rs[2] + rs[3]);
  s2 = (rq[0] + rq[1]) + (rq[2] + rq[3]);
  const float mu = s * (1.0f / 1024.0f);
  const float var = s2 * (1.0f / 1024.0f) - mu * mu;
  const float rstd = rsqrtf(var + 1e-5f);
  fx4 gm = *(const fx4*)(gamma + tid * 4);
  fx4 bt = *(const fx4*)(beta + tid * 4);
  fx4 o;
#pragma unroll
  for (int j = 0; j < 4; j++) o[j] = (v[j] - mu) * rstd * gm[j] + bt[j];
  *(fx4*)(out + (size_t)row * 1024 + tid * 4) = o;
}

// ---------------------------------------------------------------------------
extern "C" void kernel_launch(void* const* d_in, const int* in_sizes, int n_in,
                              void* d_out, int out_size, void* d_ws, size_t ws_size,
                              hipStream_t stream)
{
  const float* query = (const float*)d_in[0];
  const float* keys  = (const float*)d_in[1];
  const float* values = (const float*)d_in[2];
  const float* Wq = (const float*)d_in[3];  const float* bq = (const float*)d_in[4];
  const float* Wk = (const float*)d_in[5];  const float* bk = (const float*)d_in[6];
  const float* Wv = (const float*)d_in[7];  const float* bv = (const float*)d_in[8];
  const float* Wo = (const float*)d_in[9];  const float* bo = (const float*)d_in[10];
  const float* gamma = (const float*)d_in[11];
  const float* beta  = (const float*)d_in[12];

  float* out = (float*)d_out;                           // [B,S,E] f32
  float* avg_out = out + (size_t)Bb * Ss * Ee;          // [B,S,M] f32

  const size_t MB = 1024 * 1024;
  char* ws = (char*)d_ws;
  u16*   Qbf    = (u16*)(ws);                 // 0-8 MB   [B*S,E] bf16 (exp2-prescaled)
  u16*   Kbf    = (u16*)(ws + 8  * MB);       // 8-16 MB  [B*M,E] bf16
  u16*   Vt     = (u16*)(ws + 16 * MB);       // 16-24 MB [B,H,D,M] bf16
  u16*   qc     = (u16*)(ws + 24 * MB);       // 24-32 MB cast query (ALIVE until gemm_out: residual)
  u16*   kc     = (u16*)(ws + 32 * MB);       // 32-40 MB cast keys (dead after qkv)
  u16*   vc     = (u16*)(ws + 40 * MB);       // 40-48 MB cast values (dead after qkv)
  u16*   wqc    = (u16*)(ws + 48 * MB);       // 48-50 MB
  u16*   wkc    = (u16*)(ws + 50 * MB);       // 50-52 MB
  u16*   wvc    = (u16*)(ws + 52 * MB);       // 52-54 MB
  u16*   woc    = (u16*)(ws + 54 * MB);       // 54-56 MB (alive until gemm_out)
  float* stats  = (float*)(ws + 56 * MB);     // 56-56.25 MB [B,H,S] 1/l
  u16*   att_bf = (u16*)(ws + 32 * MB);       // 32-40 MB, reuses kc after qkv
  u16*   ybuf   = (u16*)(ws + 40 * MB);       // 40-48 MB bf16 y, reuses vc after qkv

  cast_all<<<dim3(512, 7), 256, 0, stream>>>(query, keys, values, Wq, Wk, Wv, Wo,
                                             qc, kc, vc, wqc, wkc, wvc, woc);

  gemm_qkv<<<dim3(768), 256, 0, stream>>>(qc, kc, vc, wqc, wkc, wvc,
                                          bq, bk, bv, Qbf, Kbf, Vt);

  flash_fwd<<<dim3(Ss / 128, Hh, Bb), 256, 0, stream>>>(Qbf, Kbf, Vt, att_bf, stats);
  avg_attn<<<dim3(Mm / 32, Ss / 128, Bb), 256, 0, stream>>>(Qbf, Kbf, stats, avg_out);

  gemm_out<<<dim3(256), 256, 0, stream>>>(att_bf, woc, bo, qc, ybuf);
  ln_kernel<<<dim3(Bb * Ss), 256, 0, stream>>>(ybuf, gamma, beta, out);
}

// Round 16
// 167.229 us; speedup vs baseline: 1.5054x; 1.2179x over previous
//
#include <hip/hip_runtime.h>
#include <hip/hip_bf16.h>

typedef unsigned short u16;
typedef unsigned int   u32;
typedef __attribute__((ext_vector_type(2)))  float fx2;
typedef __attribute__((ext_vector_type(4)))  float fx4;
typedef __attribute__((ext_vector_type(16))) float f32x16;
typedef __attribute__((ext_vector_type(4)))  u16   usx4;
typedef __attribute__((ext_vector_type(8)))  u16   usx8;
typedef __attribute__((ext_vector_type(8)))  __bf16 bf16x8;
typedef __attribute__((ext_vector_type(2)))  int   i32x2;
typedef __attribute__((ext_vector_type(2)))  u32   u32x2;
typedef __attribute__((ext_vector_type(4)))  u32   u32x4;

#define DEVI static __device__ __forceinline__

constexpr int Bb = 2, Ss = 2048, Mm = 2048, Ee = 1024, Hh = 16, Dd = 64;
// 1/sqrt(64) * log2(e): projections put Q in the exp2 score domain
#define QSCALE 0.18033688011112042f

DEVI u16 f2bf(float f) {
  u32 u = __builtin_bit_cast(u32, f);
  u32 r = (u + 0x7fffu + ((u >> 16) & 1u)) >> 16;
  return (u16)r;
}
DEVI float bf2f(u16 v) {
  u32 u = ((u32)v) << 16;
  return __builtin_bit_cast(float, u);
}
DEVI bf16x8 as_bf(usx8 v) { return __builtin_bit_cast(bf16x8, v); }

DEVI void gld16(const u16* g, u16* l) {
  __builtin_amdgcn_global_load_lds((const __attribute__((address_space(1))) void*)g,
                                   (__attribute__((address_space(3))) void*)l, 16, 0, 0);
}

#if __has_builtin(__builtin_amdgcn_exp2f)
DEVI float xexp2(float x) { return __builtin_amdgcn_exp2f(x); }
#else
DEVI float xexp2(float x) { return exp2f(x); }
#endif

DEVI u32 cvtpk(float lo, float hi) {
  u32 r;
  asm("v_cvt_pk_bf16_f32 %0, %1, %2" : "=v"(r) : "v"(lo), "v"(hi));
  return r;
}
DEVI bf16x8 pa_from(u32 w0, u32 w1, u32 w2, u32 w3) {
  union { u32 u[4]; usx8 v; } t;
  t.u[0] = w0; t.u[1] = w1; t.u[2] = w2; t.u[3] = w3;
  return as_bf(t.v);
}

// ---------------------------------------------------------------------------
// Pre-cast: f32 -> bf16 for the 3 inputs and 4 weight matrices.
// ---------------------------------------------------------------------------
__global__ __launch_bounds__(256)
void cast_all(const float* __restrict__ q, const float* __restrict__ k,
              const float* __restrict__ v,
              const float* __restrict__ wq, const float* __restrict__ wk,
              const float* __restrict__ wv, const float* __restrict__ wo,
              u16* __restrict__ qc, u16* __restrict__ kc, u16* __restrict__ vc,
              u16* __restrict__ wqc, u16* __restrict__ wkc,
              u16* __restrict__ wvc, u16* __restrict__ woc)
{
  const int y = blockIdx.y;
  const float* s; u16* d; size_t n;
  const size_t NI = (size_t)Bb * Ss * Ee;
  const size_t NW = (size_t)Ee * Ee;
  switch (y) {
    case 0: s = q;  d = qc;  n = NI; break;
    case 1: s = k;  d = kc;  n = NI; break;
    case 2: s = v;  d = vc;  n = NI; break;
    case 3: s = wq; d = wqc; n = NW; break;
    case 4: s = wk; d = wkc; n = NW; break;
    case 5: s = wv; d = wvc; n = NW; break;
    default: s = wo; d = woc; n = NW; break;
  }
  const size_t stride = (size_t)gridDim.x * 256 * 8;
  for (size_t i = ((size_t)blockIdx.x * 256 + threadIdx.x) * 8; i < n; i += stride) {
    fx4 a = *(const fx4*)(s + i);
    fx4 b = *(const fx4*)(s + i + 4);
    u32x4 o;
    o[0] = cvtpk(a[0], a[1]); o[1] = cvtpk(a[2], a[3]);
    o[2] = cvtpk(b[0], b[1]); o[3] = cvtpk(b[2], b[3]);
    *(u32x4*)(d + i) = o;
  }
}

// ---------------------------------------------------------------------------
// Fused Q/K/V projection GEMM (bf16 in): 128x128 tile, BK=64, 4 waves (2x2),
// global_load_lds staging with XOR swizzle, XCD-chunked block swizzle.
// ---------------------------------------------------------------------------
__global__ __launch_bounds__(256, 2)
void gemm_qkv(const u16* __restrict__ qc, const u16* __restrict__ kc,
              const u16* __restrict__ vc,
              const u16* __restrict__ wqc, const u16* __restrict__ wkc,
              const u16* __restrict__ wvc,
              const float* __restrict__ bq, const float* __restrict__ bk,
              const float* __restrict__ bv,
              u16* __restrict__ Qbf, u16* __restrict__ Kbf, u16* __restrict__ Vt)
{
  __shared__ u16 As[2][128][64];
  __shared__ u16 Bs[2][128][64];
  const int tid = threadIdx.x;
  const int w = tid >> 6, l = tid & 63, g = l >> 4, ln = l & 15;
  const int wr = w >> 1, wc = w & 1;

  const int lid = blockIdx.x;
  const int wg = (lid & 7) * 96 + (lid >> 3);
  const int z = wg >> 8;
  const int rem = wg & 255;
  const int row0 = (rem >> 3) * 128;
  const int col0 = (rem & 7) * 128;

  const u16* A = (z == 0) ? qc : (z == 1) ? kc : vc;
  const u16* W = (z == 0) ? wqc : (z == 1) ? wkc : wvc;
  const float* bias = (z == 0) ? bq : (z == 1) ? bk : bv;

  const int colu = (((l & 7) ^ (l >> 3)) << 3);
  auto stage = [&](int buf, int kt) {
#pragma unroll
    for (int j = 0; j < 4; j++) {
      const int c = j * 4 + w;
      const int row = c * 8 + (l >> 3);
      gld16(A + (size_t)(row0 + row) * 1024 + kt * 64 + colu,
            &As[buf][0][0] + c * 512 + l * 8);
      gld16(W + (size_t)(col0 + row) * 1024 + kt * 64 + colu,
            &Bs[buf][0][0] + c * 512 + l * 8);
    }
  };

  fx4 acc[4][4];
#pragma unroll
  for (int i = 0; i < 4; i++)
#pragma unroll
    for (int j = 0; j < 4; j++) acc[i][j] = fx4{0.f, 0.f, 0.f, 0.f};

  stage(0, 0);
  __syncthreads();

  const int swA = (ln & 7) << 3;
  const int NK = 1024 / 64;
  for (int kt = 0; kt < NK; kt++) {
    const int buf = kt & 1;
    if (kt + 1 < NK) stage(buf ^ 1, kt + 1);
#pragma unroll
    for (int ks = 0; ks < 2; ks++) {
      bf16x8 af[4], bfr[4];
      const int cb = (ks * 32 + g * 8) ^ swA;
#pragma unroll
      for (int mi = 0; mi < 4; mi++)
        af[mi] = as_bf(*(const usx8*)&As[buf][wr * 64 + mi * 16 + ln][cb]);
#pragma unroll
      for (int nj = 0; nj < 4; nj++)
        bfr[nj] = as_bf(*(const usx8*)&Bs[buf][wc * 64 + nj * 16 + ln][cb]);
      __builtin_amdgcn_s_setprio(1);
#pragma unroll
      for (int mi = 0; mi < 4; mi++)
#pragma unroll
        for (int nj = 0; nj < 4; nj++)
          acc[mi][nj] = __builtin_amdgcn_mfma_f32_16x16x32_bf16(af[mi], bfr[nj], acc[mi][nj], 0, 0, 0);
      __builtin_amdgcn_s_setprio(0);
    }
    __syncthreads();
  }

#pragma unroll
  for (int mi = 0; mi < 4; mi++) {
#pragma unroll
    for (int nj = 0; nj < 4; nj++) {
      const int j = col0 + wc * 64 + nj * 16 + ln;
      const float bj = bias[j];
      if (z == 2) {
        const int i0 = row0 + wr * 64 + mi * 16 + g * 4;
        const int b2 = i0 >> 11, m2 = i0 & 2047;
        const int h2 = j >> 6,  d2 = j & 63;
        u32x2 pk;
        pk[0] = cvtpk(acc[mi][nj][0] + bj, acc[mi][nj][1] + bj);
        pk[1] = cvtpk(acc[mi][nj][2] + bj, acc[mi][nj][3] + bj);
        *(u32x2*)&Vt[(((size_t)b2 * Hh + h2) * 64 + d2) * (size_t)Mm + m2] = pk;
      } else {
        u16* outp = (z == 0) ? Qbf : Kbf;
        const float sc = (z == 0) ? QSCALE : 1.0f;
#pragma unroll
        for (int r = 0; r < 4; r++) {
          const int i = row0 + wr * 64 + mi * 16 + g * 4 + r;
          outp[(size_t)i * 1024 + j] = f2bf((acc[mi][nj][r] + bj) * sc);
        }
      }
    }
  }
}

// ---------------------------------------------------------------------------
// Output GEMM: y(bf16) = attended(bf16) @ Wo(bf16).T + bo + resid(bf16).
// 128x64 tile -> grid 512 = 2 blocks/CU (was 256 = 1/CU, grid-limited).
// 4 waves (2x2: 64x32 each), BK=64, same staging pattern.
// ---------------------------------------------------------------------------
__global__ __launch_bounds__(256, 2)
void gemm_out(const u16* __restrict__ Ab, const u16* __restrict__ W,
              const float* __restrict__ bias, const u16* __restrict__ resid,
              u16* __restrict__ outb)
{
  __shared__ u16 As[2][128][64];   // 16 KB x2
  __shared__ u16 Bs[2][64][64];    // 8 KB x2
  const int tid = threadIdx.x;
  const int w = tid >> 6, l = tid & 63, g = l >> 4, ln = l & 15;
  const int wr = w >> 1, wc = w & 1;

  const int lid = blockIdx.x;                    // 512 blocks, 64/XCD
  const int wg = (lid & 7) * 64 + (lid >> 3);
  const int row0 = (wg >> 4) * 128;              // 32 row-tiles
  const int col0 = (wg & 15) * 64;               // 16 col-tiles

  const int colu = (((l & 7) ^ (l >> 3)) << 3);
  auto stage = [&](int buf, int kt) {
#pragma unroll
    for (int j = 0; j < 4; j++) {
      const int c = j * 4 + w;                   // A: 16 chunks (128 rows)
      const int row = c * 8 + (l >> 3);
      gld16(Ab + (size_t)(row0 + row) * 1024 + kt * 64 + colu,
            &As[buf][0][0] + c * 512 + l * 8);
    }
#pragma unroll
    for (int j = 0; j < 2; j++) {
      const int c = j * 4 + w;                   // B: 8 chunks (64 rows)
      const int row = c * 8 + (l >> 3);
      gld16(W + (size_t)(col0 + row) * 1024 + kt * 64 + colu,
            &Bs[buf][0][0] + c * 512 + l * 8);
    }
  };

  fx4 acc[4][2];
#pragma unroll
  for (int i = 0; i < 4; i++)
#pragma unroll
    for (int j = 0; j < 2; j++) acc[i][j] = fx4{0.f, 0.f, 0.f, 0.f};

  stage(0, 0);
  __syncthreads();

  const int swA = (ln & 7) << 3;
  const int NK = 1024 / 64;
  for (int kt = 0; kt < NK; kt++) {
    const int buf = kt & 1;
    if (kt + 1 < NK) stage(buf ^ 1, kt + 1);
#pragma unroll
    for (int ks = 0; ks < 2; ks++) {
      bf16x8 af[4], bfr[2];
      const int cb = (ks * 32 + g * 8) ^ swA;
#pragma unroll
      for (int mi = 0; mi < 4; mi++)
        af[mi] = as_bf(*(const usx8*)&As[buf][wr * 64 + mi * 16 + ln][cb]);
#pragma unroll
      for (int nj = 0; nj < 2; nj++)
        bfr[nj] = as_bf(*(const usx8*)&Bs[buf][wc * 32 + nj * 16 + ln][cb]);
      __builtin_amdgcn_s_setprio(1);
#pragma unroll
      for (int mi = 0; mi < 4; mi++)
#pragma unroll
        for (int nj = 0; nj < 2; nj++)
          acc[mi][nj] = __builtin_amdgcn_mfma_f32_16x16x32_bf16(af[mi], bfr[nj], acc[mi][nj], 0, 0, 0);
      __builtin_amdgcn_s_setprio(0);
    }
    __syncthreads();
  }

#pragma unroll
  for (int mi = 0; mi < 4; mi++) {
#pragma unroll
    for (int nj = 0; nj < 2; nj++) {
      const int j = col0 + wc * 32 + nj * 16 + ln;
      const float bj = bias[j];
#pragma unroll
      for (int r = 0; r < 4; r++) {
        const int i = row0 + wr * 64 + mi * 16 + g * 4 + r;
        const float v = acc[mi][nj][r] + bj + bf2f(resid[(size_t)i * 1024 + j]);
        outb[(size_t)i * 1024 + j] = f2bf(v);
      }
    }
  }
}

// ---------------------------------------------------------------------------
// Pass 1: flash attention, swapped-QK 32x32, no-max exp2 softmax.
// ---------------------------------------------------------------------------
__global__ __launch_bounds__(256, 2)
void flash_fwd(const u16* __restrict__ Qb, const u16* __restrict__ Kb,
               const u16* __restrict__ Vt, u16* __restrict__ attended,
               float* __restrict__ stats)
{
  __shared__ u16 Ks[2][128][64];   // 32 KB
  __shared__ u16 Vs[2][64][128];   // 32 KB
  const int tid = threadIdx.x;
  const int w = tid >> 6, l = tid & 63;
  const int ln32 = l & 31, hi = l >> 5;
  const int st = blockIdx.x, h = blockIdx.y, b = blockIdx.z;
  const int s0 = st * 128 + w * 32;

  const u16* Kbase = Kb + (size_t)b * Mm * 1024 + h * 64;
  const u16* Vbase = Vt + ((size_t)(b * Hh + h) * 64) * (size_t)Mm;

  const int colu_k = (((l & 7) ^ (l >> 3)) << 3);
  auto stage = [&](int buf, int mt) {
    const int mb = mt * 128;
#pragma unroll
    for (int j = 0; j < 4; j++) {
      const int c = j * 4 + w;
      const int krow = c * 8 + (l >> 3);
      gld16(Kbase + (size_t)(mb + krow) * 1024 + colu_k,
            &Ks[buf][0][0] + c * 512 + l * 8);
      const int vrow = c * 4 + (l >> 4);
      const int colv = (((l & 15) ^ (vrow & 15)) << 3);
      gld16(Vbase + (size_t)vrow * (size_t)Mm + mb + colv,
            &Vs[buf][0][0] + c * 512 + l * 8);
    }
  };

  bf16x8 qa[4];
#pragma unroll
  for (int dstep = 0; dstep < 4; dstep++)
    qa[dstep] = as_bf(*(const usx8*)(Qb + (size_t)(b * Ss + s0 + ln32) * Ee
                                     + h * 64 + dstep * 16 + hi * 8));

  f32x16 acc[2];
#pragma unroll
  for (int i = 0; i < 16; i++) { acc[0][i] = 0.f; acc[1][i] = 0.f; }
  float lsum = 0.f;

  stage(0, 0);
  __syncthreads();

  const int NT = Mm / 128;
  for (int mt = 0; mt < NT; mt++) {
    const int buf = mt & 1;
    if (mt + 1 < NT) stage(buf ^ 1, mt + 1);

    f32x16 sc[4];
#pragma unroll
    for (int mtile = 0; mtile < 4; mtile++) {
      const int row = mtile * 32 + ln32;
      const int sw = (row & 7) << 3;
      f32x16 c;
#pragma unroll
      for (int i = 0; i < 16; i++) c[i] = 0.f;
#pragma unroll
      for (int dstep = 0; dstep < 4; dstep++) {
        bf16x8 kf = as_bf(*(const usx8*)&Ks[buf][row][(dstep * 16 + hi * 8) ^ sw]);
        c = __builtin_amdgcn_mfma_f32_32x32x16_bf16(kf, qa[dstep], c, 0, 0, 0);
      }
      sc[mtile] = c;
    }

#pragma unroll
    for (int mtile = 0; mtile < 4; mtile++) {
      float p[16];
#pragma unroll
      for (int r = 0; r < 16; r++) p[r] = xexp2(sc[mtile][r]);
      float t0 = (p[0] + p[1]) + (p[2] + p[3]);
      float t1 = (p[4] + p[5]) + (p[6] + p[7]);
      float t2 = (p[8] + p[9]) + (p[10] + p[11]);
      float t3 = (p[12] + p[13]) + (p[14] + p[15]);
      lsum += (t0 + t1) + (t2 + t3);

      u32 cp[8];
#pragma unroll
      for (int i = 0; i < 8; i++) cp[i] = cvtpk(p[2 * i], p[2 * i + 1]);
      i32x2 sA = __builtin_amdgcn_permlane32_swap((int)cp[0], (int)cp[2], false, false);
      i32x2 sB = __builtin_amdgcn_permlane32_swap((int)cp[1], (int)cp[3], false, false);
      bf16x8 pa0 = pa_from((u32)sA.x, (u32)sB.x, (u32)sA.y, (u32)sB.y);
      i32x2 sC = __builtin_amdgcn_permlane32_swap((int)cp[4], (int)cp[6], false, false);
      i32x2 sD = __builtin_amdgcn_permlane32_swap((int)cp[5], (int)cp[7], false, false);
      bf16x8 pa1 = pa_from((u32)sC.x, (u32)sD.x, (u32)sC.y, (u32)sD.y);

#pragma unroll
      for (int dtile = 0; dtile < 2; dtile++) {
        const int vrow = dtile * 32 + ln32;
        const int vsw = (vrow & 15) << 3;
        bf16x8 vb0 = as_bf(*(const usx8*)&Vs[buf][vrow][(mtile * 32 + hi * 8) ^ vsw]);
        bf16x8 vb1 = as_bf(*(const usx8*)&Vs[buf][vrow][(mtile * 32 + 16 + hi * 8) ^ vsw]);
        acc[dtile] = __builtin_amdgcn_mfma_f32_32x32x16_bf16(pa0, vb0, acc[dtile], 0, 0, 0);
        acc[dtile] = __builtin_amdgcn_mfma_f32_32x32x16_bf16(pa1, vb1, acc[dtile], 0, 0, 0);
      }
    }
    __syncthreads();
  }

  lsum += __shfl_xor(lsum, 32);
  const float inv = 1.0f / lsum;
  if (l < 32)
    stats[(size_t)(b * Hh + h) * Ss + s0 + l] = inv;
#pragma unroll
  for (int r = 0; r < 16; r++) {
    const int srow = (r & 3) + 8 * (r >> 2) + 4 * hi;
    const float invr = __shfl(inv, srow);
    const int s_abs = s0 + srow;
#pragma unroll
    for (int dtile = 0; dtile < 2; dtile++)
      attended[(size_t)(b * Ss + s_abs) * Ee + h * 64 + dtile * 32 + ln32] =
          f2bf(acc[dtile][r] * invr);
  }
}

// ---------------------------------------------------------------------------
// Pass 2: avg_attention (r13 exact -- the empirical optimum of this
// neighborhood): m-tile 64, 3-slot K ring (24 KB), stage h+2, counted vmcnt,
// raw s_barrier, naturally-rolled head loop.
// ---------------------------------------------------------------------------
__global__ __launch_bounds__(256)
void avg_attn(const u16* __restrict__ Qb, const u16* __restrict__ Kb,
              const float* __restrict__ stats, float* __restrict__ avg_out)
{
  __shared__ u16 Ks[3][64][64];    // 24 KB, 3-slot ring (depth-2 prefetch)
  const int tid = threadIdx.x;
  const int w = tid >> 6, l = tid & 63;
  const int ln32 = l & 31, hi = l >> 5;
  const int mtile0 = blockIdx.x, stile = blockIdx.y, b = blockIdx.z;
  const int m0 = mtile0 * 64;
  const int s0 = stile * 128 + w * 32;
  const int s_lane = s0 + ln32;

  const u16* Kbase = Kb + (size_t)(b * Mm + m0) * 1024;
  const u16* Qrow  = Qb + (size_t)(b * Ss + s_lane) * Ee;
  const float* strow = stats + (size_t)b * Hh * Ss + s_lane;

  const int colu = (((l & 7) ^ (l >> 3)) << 3);
  auto stage = [&](int slot, int h) {
#pragma unroll
    for (int j = 0; j < 2; j++) {
      const int c = j * 4 + w;              // chunk 0..7 (1 KB each)
      const int row = c * 8 + (l >> 3);
      gld16(Kbase + (size_t)row * 1024 + h * 64 + colu,
            &Ks[slot][0][0] + c * 512 + l * 8);
    }
  };

  f32x16 acc[2];
#pragma unroll
  for (int i = 0; i < 16; i++) { acc[0][i] = 0.f; acc[1][i] = 0.f; }

  // prologue: slots 0,1 staged; require slot 0 landed, leave slot 1 in flight
  stage(0, 0);
  stage(1, 1);
  asm volatile("s_waitcnt vmcnt(2)" ::: "memory");
  __builtin_amdgcn_s_barrier();

  for (int h = 0; h < Hh; h++) {
    const int slot = h % 3;

    // Q + inv for this head FIRST (so the stage below is the newest vmem ops)
    bf16x8 qa[4];
#pragma unroll
    for (int d = 0; d < 4; d++)
      qa[d] = as_bf(*(const usx8*)(Qrow + h * 64 + d * 16 + hi * 8));
    const float invh = strow[(size_t)h * Ss];

    if (h + 2 < Hh) stage((h + 2) % 3, h + 2);

#pragma unroll
    for (int mtile = 0; mtile < 2; mtile++) {
      const int row = mtile * 32 + ln32;
      const int sw = (row & 7) << 3;
      f32x16 c;
#pragma unroll
      for (int i = 0; i < 16; i++) c[i] = 0.f;
      __builtin_amdgcn_s_setprio(1);
#pragma unroll
      for (int dstep = 0; dstep < 4; dstep++) {
        bf16x8 kf = as_bf(*(const usx8*)&Ks[slot][row][(dstep * 16 + hi * 8) ^ sw]);
        c = __builtin_amdgcn_mfma_f32_32x32x16_bf16(kf, qa[dstep], c, 0, 0, 0);
      }
      __builtin_amdgcn_s_setprio(0);
#pragma unroll
      for (int r = 0; r < 16; r++)
        acc[mtile][r] += xexp2(c[r]) * invh;
    }

    // counted wait: stage(h+1) must have landed; stage(h+2) may stay in flight
    if (h + 2 < Hh) {
      asm volatile("s_waitcnt vmcnt(2)" ::: "memory");
    } else {
      asm volatile("s_waitcnt vmcnt(0)" ::: "memory");
    }
    __builtin_amdgcn_s_barrier();
  }

  float* orow = avg_out + ((size_t)(b * Ss + s_lane)) * Mm + m0;
#pragma unroll
  for (int mtile = 0; mtile < 2; mtile++)
#pragma unroll
    for (int rq = 0; rq < 4; rq++) {
      fx4 o;
#pragma unroll
      for (int j = 0; j < 4; j++) o[j] = acc[mtile][rq * 4 + j] * (1.0f / 16.0f);
      *(fx4*)(orow + mtile * 32 + rq * 8 + 4 * hi) = o;
    }
}

// ---------------------------------------------------------------------------
// LayerNorm over E=1024, bf16 input y. One block (256 thr) per row.
// ---------------------------------------------------------------------------
__global__ __launch_bounds__(256)
void ln_kernel(const u16* __restrict__ yb, const float* __restrict__ gamma,
               const float* __restrict__ beta, float* __restrict__ out)
{
  const int row = blockIdx.x, tid = threadIdx.x;
  const int w = tid >> 6, l = tid & 63;
  usx4 v4 = *(const usx4*)(yb + (size_t)row * 1024 + tid * 4);
  float v[4];
#pragma unroll
  for (int j = 0; j < 4; j++) v[j] = bf2f(v4[j]);
  float s = v[0] + v[1] + v[2] + v[3];
  float s2 = v[0] * v[0] + v[1] * v[1] + v[2] * v[2] + v[3] * v[3];
#pragma unroll
  for (int off = 32; off >= 1; off >>= 1) {
    s += __shfl_xor(s, off);
    s2 += __shfl_xor(s2, off);
  }
  __shared__ float rs[4], rq[4];
  if (l == 0) { rs[w] = s; rq[w] = s2; }
  __syncthreads();
  s = (rs[0] + rs[1]) + (rs[2] + rs[3]);
  s2 = (rq[0] + rq[1]) + (rq[2] + rq[3]);
  const float mu = s * (1.0f / 1024.0f);
  const float var = s2 * (1.0f / 1024.0f) - mu * mu;
  const float rstd = rsqrtf(var + 1e-5f);
  fx4 gm = *(const fx4*)(gamma + tid * 4);
  fx4 bt = *(const fx4*)(beta + tid * 4);
  fx4 o;
#pragma unroll
  for (int j = 0; j < 4; j++) o[j] = (v[j] - mu) * rstd * gm[j] + bt[j];
  *(fx4*)(out + (size_t)row * 1024 + tid * 4) = o;
}

// ---------------------------------------------------------------------------
extern "C" void kernel_launch(void* const* d_in, const int* in_sizes, int n_in,
                              void* d_out, int out_size, void* d_ws, size_t ws_size,
                              hipStream_t stream)
{
  const float* query = (const float*)d_in[0];
  const float* keys  = (const float*)d_in[1];
  const float* values = (const float*)d_in[2];
  const float* Wq = (const float*)d_in[3];  const float* bq = (const float*)d_in[4];
  const float* Wk = (const float*)d_in[5];  const float* bk = (const float*)d_in[6];
  const float* Wv = (const float*)d_in[7];  const float* bv = (const float*)d_in[8];
  const float* Wo = (const float*)d_in[9];  const float* bo = (const float*)d_in[10];
  const float* gamma = (const float*)d_in[11];
  const float* beta  = (const float*)d_in[12];

  float* out = (float*)d_out;                           // [B,S,E] f32
  float* avg_out = out + (size_t)Bb * Ss * Ee;          // [B,S,M] f32

  const size_t MB = 1024 * 1024;
  char* ws = (char*)d_ws;
  u16*   Qbf    = (u16*)(ws);                 // 0-8 MB   [B*S,E] bf16 (exp2-prescaled)
  u16*   Kbf    = (u16*)(ws + 8  * MB);       // 8-16 MB  [B*M,E] bf16
  u16*   Vt     = (u16*)(ws + 16 * MB);       // 16-24 MB [B,H,D,M] bf16
  u16*   qc     = (u16*)(ws + 24 * MB);       // 24-32 MB cast query (ALIVE until gemm_out: residual)
  u16*   kc     = (u16*)(ws + 32 * MB);       // 32-40 MB cast keys (dead after qkv)
  u16*   vc     = (u16*)(ws + 40 * MB);       // 40-48 MB cast values (dead after qkv)
  u16*   wqc    = (u16*)(ws + 48 * MB);       // 48-50 MB
  u16*   wkc    = (u16*)(ws + 50 * MB);       // 50-52 MB
  u16*   wvc    = (u16*)(ws + 52 * MB);       // 52-54 MB
  u16*   woc    = (u16*)(ws + 54 * MB);       // 54-56 MB (alive until gemm_out)
  float* stats  = (float*)(ws + 56 * MB);     // 56-56.25 MB [B,H,S] 1/l
  u16*   att_bf = (u16*)(ws + 32 * MB);       // 32-40 MB, reuses kc after qkv
  u16*   ybuf   = (u16*)(ws + 40 * MB);       // 40-48 MB bf16 y, reuses vc after qkv

  cast_all<<<dim3(512, 7), 256, 0, stream>>>(query, keys, values, Wq, Wk, Wv, Wo,
                                             qc, kc, vc, wqc, wkc, wvc, woc);

  gemm_qkv<<<dim3(768), 256, 0, stream>>>(qc, kc, vc, wqc, wkc, wvc,
                                          bq, bk, bv, Qbf, Kbf, Vt);

  flash_fwd<<<dim3(Ss / 128, Hh, Bb), 256, 0, stream>>>(Qbf, Kbf, Vt, att_bf, stats);
  avg_attn<<<dim3(Mm / 64, Ss / 128, Bb), 256, 0, stream>>>(Qbf, Kbf, stats, avg_out);

  gemm_out<<<dim3(512), 256, 0, stream>>>(att_bf, woc, bo, qc, ybuf);
  ln_kernel<<<dim3(Bb * Ss), 256, 0, stream>>>(ybuf, gamma, beta, out);
}

// Round 17
// 161.070 us; speedup vs baseline: 1.5630x; 1.0382x over previous
//
#include <hip/hip_runtime.h>
#include <hip/hip_bf16.h>

typedef unsigned short u16;
typedef unsigned int   u32;
typedef __attribute__((ext_vector_type(2)))  float fx2;
typedef __attribute__((ext_vector_type(4)))  float fx4;
typedef __attribute__((ext_vector_type(16))) float f32x16;
typedef __attribute__((ext_vector_type(4)))  u16   usx4;
typedef __attribute__((ext_vector_type(8)))  u16   usx8;
typedef __attribute__((ext_vector_type(8)))  __bf16 bf16x8;
typedef __attribute__((ext_vector_type(2)))  int   i32x2;
typedef __attribute__((ext_vector_type(2)))  u32   u32x2;
typedef __attribute__((ext_vector_type(4)))  u32   u32x4;

#define DEVI static __device__ __forceinline__

constexpr int Bb = 2, Ss = 2048, Mm = 2048, Ee = 1024, Hh = 16, Dd = 64;
// 1/sqrt(64) * log2(e): projections put Q in the exp2 score domain
#define QSCALE 0.18033688011112042f

DEVI u16 f2bf(float f) {
  u32 u = __builtin_bit_cast(u32, f);
  u32 r = (u + 0x7fffu + ((u >> 16) & 1u)) >> 16;
  return (u16)r;
}
DEVI float bf2f(u16 v) {
  u32 u = ((u32)v) << 16;
  return __builtin_bit_cast(float, u);
}
DEVI bf16x8 as_bf(usx8 v) { return __builtin_bit_cast(bf16x8, v); }

DEVI void gld16(const u16* g, u16* l) {
  __builtin_amdgcn_global_load_lds((const __attribute__((address_space(1))) void*)g,
                                   (__attribute__((address_space(3))) void*)l, 16, 0, 0);
}

#if __has_builtin(__builtin_amdgcn_exp2f)
DEVI float xexp2(float x) { return __builtin_amdgcn_exp2f(x); }
#else
DEVI float xexp2(float x) { return exp2f(x); }
#endif

DEVI u32 cvtpk(float lo, float hi) {
  u32 r;
  asm("v_cvt_pk_bf16_f32 %0, %1, %2" : "=v"(r) : "v"(lo), "v"(hi));
  return r;
}
DEVI bf16x8 pa_from(u32 w0, u32 w1, u32 w2, u32 w3) {
  union { u32 u[4]; usx8 v; } t;
  t.u[0] = w0; t.u[1] = w1; t.u[2] = w2; t.u[3] = w3;
  return as_bf(t.v);
}

// ---------------------------------------------------------------------------
// Pre-cast: f32 -> bf16 for the 3 inputs and 4 weight matrices.
// ---------------------------------------------------------------------------
__global__ __launch_bounds__(256)
void cast_all(const float* __restrict__ q, const float* __restrict__ k,
              const float* __restrict__ v,
              const float* __restrict__ wq, const float* __restrict__ wk,
              const float* __restrict__ wv, const float* __restrict__ wo,
              u16* __restrict__ qc, u16* __restrict__ kc, u16* __restrict__ vc,
              u16* __restrict__ wqc, u16* __restrict__ wkc,
              u16* __restrict__ wvc, u16* __restrict__ woc)
{
  const int y = blockIdx.y;
  const float* s; u16* d; size_t n;
  const size_t NI = (size_t)Bb * Ss * Ee;
  const size_t NW = (size_t)Ee * Ee;
  switch (y) {
    case 0: s = q;  d = qc;  n = NI; break;
    case 1: s = k;  d = kc;  n = NI; break;
    case 2: s = v;  d = vc;  n = NI; break;
    case 3: s = wq; d = wqc; n = NW; break;
    case 4: s = wk; d = wkc; n = NW; break;
    case 5: s = wv; d = wvc; n = NW; break;
    default: s = wo; d = woc; n = NW; break;
  }
  const size_t stride = (size_t)gridDim.x * 256 * 8;
  for (size_t i = ((size_t)blockIdx.x * 256 + threadIdx.x) * 8; i < n; i += stride) {
    fx4 a = *(const fx4*)(s + i);
    fx4 b = *(const fx4*)(s + i + 4);
    u32x4 o;
    o[0] = cvtpk(a[0], a[1]); o[1] = cvtpk(a[2], a[3]);
    o[2] = cvtpk(b[0], b[1]); o[3] = cvtpk(b[2], b[3]);
    *(u32x4*)(d + i) = o;
  }
}

// ---------------------------------------------------------------------------
// Fused Q/K/V projection GEMM (bf16 in): 128x64 tile (grid 1536 = 3 blocks/CU
// after 48 KB LDS), BK=64, 4 waves (2x2: 64x32 each), global_load_lds staging
// with XOR swizzle, bijective XCD-chunked block swizzle (1536 = 8 x 192).
// z in {0:Q(scaled), 1:K, 2:V(transposed [B,H,D,M])}.
// ---------------------------------------------------------------------------
__global__ __launch_bounds__(256, 2)
void gemm_qkv(const u16* __restrict__ qc, const u16* __restrict__ kc,
              const u16* __restrict__ vc,
              const u16* __restrict__ wqc, const u16* __restrict__ wkc,
              const u16* __restrict__ wvc,
              const float* __restrict__ bq, const float* __restrict__ bk,
              const float* __restrict__ bv,
              u16* __restrict__ Qbf, u16* __restrict__ Kbf, u16* __restrict__ Vt)
{
  __shared__ u16 As[2][128][64];   // 16 KB x2
  __shared__ u16 Bs[2][64][64];    // 8 KB x2
  const int tid = threadIdx.x;
  const int w = tid >> 6, l = tid & 63, g = l >> 4, ln = l & 15;
  const int wr = w >> 1, wc = w & 1;

  const int lid = blockIdx.x;                    // 1536 blocks, 192/XCD
  const int wg = (lid & 7) * 192 + (lid >> 3);
  const int z = wg >> 9;                         // 512 blocks per z
  const int rem = wg & 511;
  const int row0 = (rem >> 4) * 128;             // 32 row-tiles
  const int col0 = (rem & 15) * 64;              // 16 col-tiles

  const u16* A = (z == 0) ? qc : (z == 1) ? kc : vc;
  const u16* W = (z == 0) ? wqc : (z == 1) ? wkc : wvc;
  const float* bias = (z == 0) ? bq : (z == 1) ? bk : bv;

  const int colu = (((l & 7) ^ (l >> 3)) << 3);
  auto stage = [&](int buf, int kt) {
#pragma unroll
    for (int j = 0; j < 4; j++) {
      const int c = j * 4 + w;                   // A: 16 chunks (128 rows)
      const int row = c * 8 + (l >> 3);
      gld16(A + (size_t)(row0 + row) * 1024 + kt * 64 + colu,
            &As[buf][0][0] + c * 512 + l * 8);
    }
#pragma unroll
    for (int j = 0; j < 2; j++) {
      const int c = j * 4 + w;                   // B: 8 chunks (64 rows)
      const int row = c * 8 + (l >> 3);
      gld16(W + (size_t)(col0 + row) * 1024 + kt * 64 + colu,
            &Bs[buf][0][0] + c * 512 + l * 8);
    }
  };

  fx4 acc[4][2];
#pragma unroll
  for (int i = 0; i < 4; i++)
#pragma unroll
    for (int j = 0; j < 2; j++) acc[i][j] = fx4{0.f, 0.f, 0.f, 0.f};

  stage(0, 0);
  __syncthreads();

  const int swA = (ln & 7) << 3;
  const int NK = 1024 / 64;
  for (int kt = 0; kt < NK; kt++) {
    const int buf = kt & 1;
    if (kt + 1 < NK) stage(buf ^ 1, kt + 1);
#pragma unroll
    for (int ks = 0; ks < 2; ks++) {
      bf16x8 af[4], bfr[2];
      const int cb = (ks * 32 + g * 8) ^ swA;
#pragma unroll
      for (int mi = 0; mi < 4; mi++)
        af[mi] = as_bf(*(const usx8*)&As[buf][wr * 64 + mi * 16 + ln][cb]);
#pragma unroll
      for (int nj = 0; nj < 2; nj++)
        bfr[nj] = as_bf(*(const usx8*)&Bs[buf][wc * 32 + nj * 16 + ln][cb]);
      __builtin_amdgcn_s_setprio(1);
#pragma unroll
      for (int mi = 0; mi < 4; mi++)
#pragma unroll
        for (int nj = 0; nj < 2; nj++)
          acc[mi][nj] = __builtin_amdgcn_mfma_f32_16x16x32_bf16(af[mi], bfr[nj], acc[mi][nj], 0, 0, 0);
      __builtin_amdgcn_s_setprio(0);
    }
    __syncthreads();
  }

#pragma unroll
  for (int mi = 0; mi < 4; mi++) {
#pragma unroll
    for (int nj = 0; nj < 2; nj++) {
      const int j = col0 + wc * 32 + nj * 16 + ln;
      const float bj = bias[j];
      if (z == 2) {
        // i consecutive in r -> m consecutive: pack 4 bf16, one b64 store
        const int i0 = row0 + wr * 64 + mi * 16 + g * 4;
        const int b2 = i0 >> 11, m2 = i0 & 2047;
        const int h2 = j >> 6,  d2 = j & 63;
        u32x2 pk;
        pk[0] = cvtpk(acc[mi][nj][0] + bj, acc[mi][nj][1] + bj);
        pk[1] = cvtpk(acc[mi][nj][2] + bj, acc[mi][nj][3] + bj);
        *(u32x2*)&Vt[(((size_t)b2 * Hh + h2) * 64 + d2) * (size_t)Mm + m2] = pk;
      } else {
        u16* outp = (z == 0) ? Qbf : Kbf;
        const float sc = (z == 0) ? QSCALE : 1.0f;
#pragma unroll
        for (int r = 0; r < 4; r++) {
          const int i = row0 + wr * 64 + mi * 16 + g * 4 + r;
          outp[(size_t)i * 1024 + j] = f2bf((acc[mi][nj][r] + bj) * sc);
        }
      }
    }
  }
}

// ---------------------------------------------------------------------------
// Output GEMM: y(bf16) = attended(bf16) @ Wo(bf16).T + bo + resid(bf16).
// 128x64 tile -> grid 512 = 2 blocks/CU. 4 waves (2x2: 64x32 each), BK=64.
// ---------------------------------------------------------------------------
__global__ __launch_bounds__(256, 2)
void gemm_out(const u16* __restrict__ Ab, const u16* __restrict__ W,
              const float* __restrict__ bias, const u16* __restrict__ resid,
              u16* __restrict__ outb)
{
  __shared__ u16 As[2][128][64];   // 16 KB x2
  __shared__ u16 Bs[2][64][64];    // 8 KB x2
  const int tid = threadIdx.x;
  const int w = tid >> 6, l = tid & 63, g = l >> 4, ln = l & 15;
  const int wr = w >> 1, wc = w & 1;

  const int lid = blockIdx.x;                    // 512 blocks, 64/XCD
  const int wg = (lid & 7) * 64 + (lid >> 3);
  const int row0 = (wg >> 4) * 128;              // 32 row-tiles
  const int col0 = (wg & 15) * 64;               // 16 col-tiles

  const int colu = (((l & 7) ^ (l >> 3)) << 3);
  auto stage = [&](int buf, int kt) {
#pragma unroll
    for (int j = 0; j < 4; j++) {
      const int c = j * 4 + w;                   // A: 16 chunks (128 rows)
      const int row = c * 8 + (l >> 3);
      gld16(Ab + (size_t)(row0 + row) * 1024 + kt * 64 + colu,
            &As[buf][0][0] + c * 512 + l * 8);
    }
#pragma unroll
    for (int j = 0; j < 2; j++) {
      const int c = j * 4 + w;                   // B: 8 chunks (64 rows)
      const int row = c * 8 + (l >> 3);
      gld16(W + (size_t)(col0 + row) * 1024 + kt * 64 + colu,
            &Bs[buf][0][0] + c * 512 + l * 8);
    }
  };

  fx4 acc[4][2];
#pragma unroll
  for (int i = 0; i < 4; i++)
#pragma unroll
    for (int j = 0; j < 2; j++) acc[i][j] = fx4{0.f, 0.f, 0.f, 0.f};

  stage(0, 0);
  __syncthreads();

  const int swA = (ln & 7) << 3;
  const int NK = 1024 / 64;
  for (int kt = 0; kt < NK; kt++) {
    const int buf = kt & 1;
    if (kt + 1 < NK) stage(buf ^ 1, kt + 1);
#pragma unroll
    for (int ks = 0; ks < 2; ks++) {
      bf16x8 af[4], bfr[2];
      const int cb = (ks * 32 + g * 8) ^ swA;
#pragma unroll
      for (int mi = 0; mi < 4; mi++)
        af[mi] = as_bf(*(const usx8*)&As[buf][wr * 64 + mi * 16 + ln][cb]);
#pragma unroll
      for (int nj = 0; nj < 2; nj++)
        bfr[nj] = as_bf(*(const usx8*)&Bs[buf][wc * 32 + nj * 16 + ln][cb]);
      __builtin_amdgcn_s_setprio(1);
#pragma unroll
      for (int mi = 0; mi < 4; mi++)
#pragma unroll
        for (int nj = 0; nj < 2; nj++)
          acc[mi][nj] = __builtin_amdgcn_mfma_f32_16x16x32_bf16(af[mi], bfr[nj], acc[mi][nj], 0, 0, 0);
      __builtin_amdgcn_s_setprio(0);
    }
    __syncthreads();
  }

#pragma unroll
  for (int mi = 0; mi < 4; mi++) {
#pragma unroll
    for (int nj = 0; nj < 2; nj++) {
      const int j = col0 + wc * 32 + nj * 16 + ln;
      const float bj = bias[j];
#pragma unroll
      for (int r = 0; r < 4; r++) {
        const int i = row0 + wr * 64 + mi * 16 + g * 4 + r;
        const float v = acc[mi][nj][r] + bj + bf2f(resid[(size_t)i * 1024 + j]);
        outb[(size_t)i * 1024 + j] = f2bf(v);
      }
    }
  }
}

// ---------------------------------------------------------------------------
// Pass 1: flash attention, swapped-QK 32x32, no-max exp2 softmax.
// ---------------------------------------------------------------------------
__global__ __launch_bounds__(256, 2)
void flash_fwd(const u16* __restrict__ Qb, const u16* __restrict__ Kb,
               const u16* __restrict__ Vt, u16* __restrict__ attended,
               float* __restrict__ stats)
{
  __shared__ u16 Ks[2][128][64];   // 32 KB
  __shared__ u16 Vs[2][64][128];   // 32 KB
  const int tid = threadIdx.x;
  const int w = tid >> 6, l = tid & 63;
  const int ln32 = l & 31, hi = l >> 5;
  const int st = blockIdx.x, h = blockIdx.y, b = blockIdx.z;
  const int s0 = st * 128 + w * 32;

  const u16* Kbase = Kb + (size_t)b * Mm * 1024 + h * 64;
  const u16* Vbase = Vt + ((size_t)(b * Hh + h) * 64) * (size_t)Mm;

  const int colu_k = (((l & 7) ^ (l >> 3)) << 3);
  auto stage = [&](int buf, int mt) {
    const int mb = mt * 128;
#pragma unroll
    for (int j = 0; j < 4; j++) {
      const int c = j * 4 + w;
      const int krow = c * 8 + (l >> 3);
      gld16(Kbase + (size_t)(mb + krow) * 1024 + colu_k,
            &Ks[buf][0][0] + c * 512 + l * 8);
      const int vrow = c * 4 + (l >> 4);
      const int colv = (((l & 15) ^ (vrow & 15)) << 3);
      gld16(Vbase + (size_t)vrow * (size_t)Mm + mb + colv,
            &Vs[buf][0][0] + c * 512 + l * 8);
    }
  };

  bf16x8 qa[4];
#pragma unroll
  for (int dstep = 0; dstep < 4; dstep++)
    qa[dstep] = as_bf(*(const usx8*)(Qb + (size_t)(b * Ss + s0 + ln32) * Ee
                                     + h * 64 + dstep * 16 + hi * 8));

  f32x16 acc[2];
#pragma unroll
  for (int i = 0; i < 16; i++) { acc[0][i] = 0.f; acc[1][i] = 0.f; }
  float lsum = 0.f;

  stage(0, 0);
  __syncthreads();

  const int NT = Mm / 128;
  for (int mt = 0; mt < NT; mt++) {
    const int buf = mt & 1;
    if (mt + 1 < NT) stage(buf ^ 1, mt + 1);

    f32x16 sc[4];
#pragma unroll
    for (int mtile = 0; mtile < 4; mtile++) {
      const int row = mtile * 32 + ln32;
      const int sw = (row & 7) << 3;
      f32x16 c;
#pragma unroll
      for (int i = 0; i < 16; i++) c[i] = 0.f;
#pragma unroll
      for (int dstep = 0; dstep < 4; dstep++) {
        bf16x8 kf = as_bf(*(const usx8*)&Ks[buf][row][(dstep * 16 + hi * 8) ^ sw]);
        c = __builtin_amdgcn_mfma_f32_32x32x16_bf16(kf, qa[dstep], c, 0, 0, 0);
      }
      sc[mtile] = c;
    }

#pragma unroll
    for (int mtile = 0; mtile < 4; mtile++) {
      float p[16];
#pragma unroll
      for (int r = 0; r < 16; r++) p[r] = xexp2(sc[mtile][r]);
      float t0 = (p[0] + p[1]) + (p[2] + p[3]);
      float t1 = (p[4] + p[5]) + (p[6] + p[7]);
      float t2 = (p[8] + p[9]) + (p[10] + p[11]);
      float t3 = (p[12] + p[13]) + (p[14] + p[15]);
      lsum += (t0 + t1) + (t2 + t3);

      u32 cp[8];
#pragma unroll
      for (int i = 0; i < 8; i++) cp[i] = cvtpk(p[2 * i], p[2 * i + 1]);
      i32x2 sA = __builtin_amdgcn_permlane32_swap((int)cp[0], (int)cp[2], false, false);
      i32x2 sB = __builtin_amdgcn_permlane32_swap((int)cp[1], (int)cp[3], false, false);
      bf16x8 pa0 = pa_from((u32)sA.x, (u32)sB.x, (u32)sA.y, (u32)sB.y);
      i32x2 sC = __builtin_amdgcn_permlane32_swap((int)cp[4], (int)cp[6], false, false);
      i32x2 sD = __builtin_amdgcn_permlane32_swap((int)cp[5], (int)cp[7], false, false);
      bf16x8 pa1 = pa_from((u32)sC.x, (u32)sD.x, (u32)sC.y, (u32)sD.y);

#pragma unroll
      for (int dtile = 0; dtile < 2; dtile++) {
        const int vrow = dtile * 32 + ln32;
        const int vsw = (vrow & 15) << 3;
        bf16x8 vb0 = as_bf(*(const usx8*)&Vs[buf][vrow][(mtile * 32 + hi * 8) ^ vsw]);
        bf16x8 vb1 = as_bf(*(const usx8*)&Vs[buf][vrow][(mtile * 32 + 16 + hi * 8) ^ vsw]);
        acc[dtile] = __builtin_amdgcn_mfma_f32_32x32x16_bf16(pa0, vb0, acc[dtile], 0, 0, 0);
        acc[dtile] = __builtin_amdgcn_mfma_f32_32x32x16_bf16(pa1, vb1, acc[dtile], 0, 0, 0);
      }
    }
    __syncthreads();
  }

  lsum += __shfl_xor(lsum, 32);
  const float inv = 1.0f / lsum;
  if (l < 32)
    stats[(size_t)(b * Hh + h) * Ss + s0 + l] = inv;
#pragma unroll
  for (int r = 0; r < 16; r++) {
    const int srow = (r & 3) + 8 * (r >> 2) + 4 * hi;
    const float invr = __shfl(inv, srow);
    const int s_abs = s0 + srow;
#pragma unroll
    for (int dtile = 0; dtile < 2; dtile++)
      attended[(size_t)(b * Ss + s_abs) * Ee + h * 64 + dtile * 32 + ln32] =
          f2bf(acc[dtile][r] * invr);
  }
}

// ---------------------------------------------------------------------------
// Pass 2: avg_attention (r13 exact -- the empirical optimum of this
// neighborhood): m-tile 64, 3-slot K ring (24 KB), stage h+2, counted vmcnt,
// raw s_barrier, naturally-rolled head loop.
// ---------------------------------------------------------------------------
__global__ __launch_bounds__(256)
void avg_attn(const u16* __restrict__ Qb, const u16* __restrict__ Kb,
              const float* __restrict__ stats, float* __restrict__ avg_out)
{
  __shared__ u16 Ks[3][64][64];    // 24 KB, 3-slot ring (depth-2 prefetch)
  const int tid = threadIdx.x;
  const int w = tid >> 6, l = tid & 63;
  const int ln32 = l & 31, hi = l >> 5;
  const int mtile0 = blockIdx.x, stile = blockIdx.y, b = blockIdx.z;
  const int m0 = mtile0 * 64;
  const int s0 = stile * 128 + w * 32;
  const int s_lane = s0 + ln32;

  const u16* Kbase = Kb + (size_t)(b * Mm + m0) * 1024;
  const u16* Qrow  = Qb + (size_t)(b * Ss + s_lane) * Ee;
  const float* strow = stats + (size_t)b * Hh * Ss + s_lane;

  const int colu = (((l & 7) ^ (l >> 3)) << 3);
  auto stage = [&](int slot, int h) {
#pragma unroll
    for (int j = 0; j < 2; j++) {
      const int c = j * 4 + w;              // chunk 0..7 (1 KB each)
      const int row = c * 8 + (l >> 3);
      gld16(Kbase + (size_t)row * 1024 + h * 64 + colu,
            &Ks[slot][0][0] + c * 512 + l * 8);
    }
  };

  f32x16 acc[2];
#pragma unroll
  for (int i = 0; i < 16; i++) { acc[0][i] = 0.f; acc[1][i] = 0.f; }

  // prologue: slots 0,1 staged; require slot 0 landed, leave slot 1 in flight
  stage(0, 0);
  stage(1, 1);
  asm volatile("s_waitcnt vmcnt(2)" ::: "memory");
  __builtin_amdgcn_s_barrier();

  for (int h = 0; h < Hh; h++) {
    const int slot = h % 3;

    // Q + inv for this head FIRST (so the stage below is the newest vmem ops)
    bf16x8 qa[4];
#pragma unroll
    for (int d = 0; d < 4; d++)
      qa[d] = as_bf(*(const usx8*)(Qrow + h * 64 + d * 16 + hi * 8));
    const float invh = strow[(size_t)h * Ss];

    if (h + 2 < Hh) stage((h + 2) % 3, h + 2);

#pragma unroll
    for (int mtile = 0; mtile < 2; mtile++) {
      const int row = mtile * 32 + ln32;
      const int sw = (row & 7) << 3;
      f32x16 c;
#pragma unroll
      for (int i = 0; i < 16; i++) c[i] = 0.f;
      __builtin_amdgcn_s_setprio(1);
#pragma unroll
      for (int dstep = 0; dstep < 4; dstep++) {
        bf16x8 kf = as_bf(*(const usx8*)&Ks[slot][row][(dstep * 16 + hi * 8) ^ sw]);
        c = __builtin_amdgcn_mfma_f32_32x32x16_bf16(kf, qa[dstep], c, 0, 0, 0);
      }
      __builtin_amdgcn_s_setprio(0);
#pragma unroll
      for (int r = 0; r < 16; r++)
        acc[mtile][r] += xexp2(c[r]) * invh;
    }

    // counted wait: stage(h+1) must have landed; stage(h+2) may stay in flight
    if (h + 2 < Hh) {
      asm volatile("s_waitcnt vmcnt(2)" ::: "memory");
    } else {
      asm volatile("s_waitcnt vmcnt(0)" ::: "memory");
    }
    __builtin_amdgcn_s_barrier();
  }

  float* orow = avg_out + ((size_t)(b * Ss + s_lane)) * Mm + m0;
#pragma unroll
  for (int mtile = 0; mtile < 2; mtile++)
#pragma unroll
    for (int rq = 0; rq < 4; rq++) {
      fx4 o;
#pragma unroll
      for (int j = 0; j < 4; j++) o[j] = acc[mtile][rq * 4 + j] * (1.0f / 16.0f);
      *(fx4*)(orow + mtile * 32 + rq * 8 + 4 * hi) = o;
    }
}

// ---------------------------------------------------------------------------
// LayerNorm over E=1024, bf16 input y. One block (256 thr) per row.
// ---------------------------------------------------------------------------
__global__ __launch_bounds__(256)
void ln_kernel(const u16* __restrict__ yb, const float* __restrict__ gamma,
               const float* __restrict__ beta, float* __restrict__ out)
{
  const int row = blockIdx.x, tid = threadIdx.x;
  const int w = tid >> 6, l = tid & 63;
  usx4 v4 = *(const usx4*)(yb + (size_t)row * 1024 + tid * 4);
  float v[4];
#pragma unroll
  for (int j = 0; j < 4; j++) v[j] = bf2f(v4[j]);
  float s = v[0] + v[1] + v[2] + v[3];
  float s2 = v[0] * v[0] + v[1] * v[1] + v[2] * v[2] + v[3] * v[3];
#pragma unroll
  for (int off = 32; off >= 1; off >>= 1) {
    s += __shfl_xor(s, off);
    s2 += __shfl_xor(s2, off);
  }
  __shared__ float rs[4], rq[4];
  if (l == 0) { rs[w] = s; rq[w] = s2; }
  __syncthreads();
  s = (rs[0] + rs[1]) + (rs[2] + rs[3]);
  s2 = (rq[0] + rq[1]) + (rq[2] + rq[3]);
  const float mu = s * (1.0f / 1024.0f);
  const float var = s2 * (1.0f / 1024.0f) - mu * mu;
  const float rstd = rsqrtf(var + 1e-5f);
  fx4 gm = *(const fx4*)(gamma + tid * 4);
  fx4 bt = *(const fx4*)(beta + tid * 4);
  fx4 o;
#pragma unroll
  for (int j = 0; j < 4; j++) o[j] = (v[j] - mu) * rstd * gm[j] + bt[j];
  *(fx4*)(out + (size_t)row * 1024 + tid * 4) = o;
}

// ---------------------------------------------------------------------------
extern "C" void kernel_launch(void* const* d_in, const int* in_sizes, int n_in,
                              void* d_out, int out_size, void* d_ws, size_t ws_size,
                              hipStream_t stream)
{
  const float* query = (const float*)d_in[0];
  const float* keys  = (const float*)d_in[1];
  const float* values = (const float*)d_in[2];
  const float* Wq = (const float*)d_in[3];  const float* bq = (const float*)d_in[4];
  const float* Wk = (const float*)d_in[5];  const float* bk = (const float*)d_in[6];
  const float* Wv = (const float*)d_in[7];  const float* bv = (const float*)d_in[8];
  const float* Wo = (const float*)d_in[9];  const float* bo = (const float*)d_in[10];
  const float* gamma = (const float*)d_in[11];
  const float* beta  = (const float*)d_in[12];

  float* out = (float*)d_out;                           // [B,S,E] f32
  float* avg_out = out + (size_t)Bb * Ss * Ee;          // [B,S,M] f32

  const size_t MB = 1024 * 1024;
  char* ws = (char*)d_ws;
  u16*   Qbf    = (u16*)(ws);                 // 0-8 MB   [B*S,E] bf16 (exp2-prescaled)
  u16*   Kbf    = (u16*)(ws + 8  * MB);       // 8-16 MB  [B*M,E] bf16
  u16*   Vt     = (u16*)(ws + 16 * MB);       // 16-24 MB [B,H,D,M] bf16
  u16*   qc     = (u16*)(ws + 24 * MB);       // 24-32 MB cast query (ALIVE until gemm_out: residual)
  u16*   kc     = (u16*)(ws + 32 * MB);       // 32-40 MB cast keys (dead after qkv)
  u16*   vc     = (u16*)(ws + 40 * MB);       // 40-48 MB cast values (dead after qkv)
  u16*   wqc    = (u16*)(ws + 48 * MB);       // 48-50 MB
  u16*   wkc    = (u16*)(ws + 50 * MB);       // 50-52 MB
  u16*   wvc    = (u16*)(ws + 52 * MB);       // 52-54 MB
  u16*   woc    = (u16*)(ws + 54 * MB);       // 54-56 MB (alive until gemm_out)
  float* stats  = (float*)(ws + 56 * MB);     // 56-56.25 MB [B,H,S] 1/l
  u16*   att_bf = (u16*)(ws + 32 * MB);       // 32-40 MB, reuses kc after qkv
  u16*   ybuf   = (u16*)(ws + 40 * MB);       // 40-48 MB bf16 y, reuses vc after qkv

  cast_all<<<dim3(512, 7), 256, 0, stream>>>(query, keys, values, Wq, Wk, Wv, Wo,
                                             qc, kc, vc, wqc, wkc, wvc, woc);

  gemm_qkv<<<dim3(1536), 256, 0, stream>>>(qc, kc, vc, wqc, wkc, wvc,
                                           bq, bk, bv, Qbf, Kbf, Vt);

  flash_fwd<<<dim3(Ss / 128, Hh, Bb), 256, 0, stream>>>(Qbf, Kbf, Vt, att_bf, stats);
  avg_attn<<<dim3(Mm / 64, Ss / 128, Bb), 256, 0, stream>>>(Qbf, Kbf, stats, avg_out);

  gemm_out<<<dim3(512), 256, 0, stream>>>(att_bf, woc, bo, qc, ybuf);
  ln_kernel<<<dim3(Bb * Ss), 256, 0, stream>>>(ybuf, gamma, beta, out);
}